// Round 1
// baseline (254.621 us; speedup 1.0000x reference)
//
#include <hip/hip_runtime.h>
#include <stdint.h>

typedef __attribute__((ext_vector_type(8))) short s8v;
typedef __attribute__((ext_vector_type(4))) short s4v;
typedef __attribute__((ext_vector_type(4))) float f4v;
typedef __attribute__((ext_vector_type(4))) unsigned short us4v;
typedef __attribute__((ext_vector_type(4))) float f32x4v;

#define DEV static __device__ __forceinline__

DEV unsigned short f2bf(float f){
  uint32_t x = __builtin_bit_cast(uint32_t, f);
  uint32_t r = x + 0x7fffu + ((x >> 16) & 1u);
  return (unsigned short)(r >> 16);
}

DEV f4v mfma32(s8v a, s8v b, f4v c){
  return __builtin_amdgcn_mfma_f32_16x16x32_bf16(a, b, c, 0, 0, 0);
}
DEV f4v mfma16(s4v a, s4v b, f4v c){
  return __builtin_amdgcn_mfma_f32_16x16x16bf16_1k(a, b, c, 0, 0, 0);
}

DEV void load_lds16(const void* g, void* l){
  __builtin_amdgcn_global_load_lds((const __attribute__((address_space(1))) uint32_t*)g,
                                   (__attribute__((address_space(3))) uint32_t*)l, 16, 0, 0);
}

// ---------------- prep: xs = concat(vp, x) -> bf16 ----------------
__global__ void k_prep_xs(const float* __restrict__ x, const float* __restrict__ vp,
                          unsigned short* __restrict__ xs){
  int64_t e = ((int64_t)blockIdx.x * 256 + threadIdx.x) * 4;
  int m = (int)(e / 768); int c = (int)(e % 768);
  int b = m / 1032, n = m % 1032;
  const float* src = (n < 8) ? (vp + ((int64_t)(b * 8 + n)) * 768 + c)
                             : (x  + ((int64_t)(b * 1024 + (n - 8))) * 768 + c);
  f32x4v v = *(const f32x4v*)src;
  us4v o = { f2bf(v[0]), f2bf(v[1]), f2bf(v[2]), f2bf(v[3]) };
  *(us4v*)(xs + e) = o;
}

// ---------------- prep: W transposes -> bf16 ----------------
__global__ void k_prep_w(const float* __restrict__ qw, const float* __restrict__ pw,
                         unsigned short* __restrict__ Wt, unsigned short* __restrict__ Pt){
  int64_t idx = (int64_t)blockIdx.x * 256 + threadIdx.x;
  if (idx < (int64_t)2304 * 768){
    int j = (int)(idx / 768), k = (int)(idx % 768);
    Wt[idx] = f2bf(qw[(int64_t)k * 2304 + j]);
  } else {
    int64_t t = idx - (int64_t)2304 * 768;
    if (t < (int64_t)768 * 768){
      int j = (int)(t / 768), k = (int)(t % 768);
      Pt[t] = f2bf(pw[(int64_t)k * 768 + j]);
    }
  }
}

// ---------------- GEMM: C = A[M,K] * Bt[N,K]^T + bias ----------------
// MODE 0: qkv epilogue (scatter to q/k/vT bf16 buffers)
// MODE 1: proj epilogue (f32 to d_out with row remap)
template<int MODE>
__global__ __launch_bounds__(256) void k_gemm(
    const unsigned short* __restrict__ A, const unsigned short* __restrict__ Bt,
    const float* __restrict__ bias, int M, int N, int K,
    unsigned short* __restrict__ qb, unsigned short* __restrict__ kb,
    unsigned short* __restrict__ vtb, float* __restrict__ outp)
{
  __shared__ __align__(16) unsigned short At [128 * 32];
  __shared__ __align__(16) unsigned short Btl[128 * 32];
  const int tid = threadIdx.x, lane = tid & 63, wid = tid >> 6;
  const int mbase = blockIdx.y * 128, nbase = blockIdx.x * 128;
  const int wr = wid >> 1, wc = wid & 1;
  const int g = lane >> 4, l15 = lane & 15;
  const int l2 = lane >> 2, l3 = lane & 3;
  f4v acc[4][4] = {};

  int srow0 = wid * 16 + l2;
  int srow1 = 64 + wid * 16 + l2;
  int sg0 = l3 ^ ((srow0 >> 1) & 3);
  int sg1 = l3 ^ ((srow1 >> 1) & 3);
  int arow0 = mbase + srow0; if (arow0 >= M) arow0 = 0;
  int arow1 = mbase + srow1; if (arow1 >= M) arow1 = 0;
  const unsigned short* a0 = A  + (int64_t)arow0 * K + sg0 * 8;
  const unsigned short* a1 = A  + (int64_t)arow1 * K + sg1 * 8;
  const unsigned short* b0 = Bt + (int64_t)(nbase + srow0) * K + sg0 * 8;
  const unsigned short* b1 = Bt + (int64_t)(nbase + srow1) * K + sg1 * 8;
  unsigned short* lA0 = At  + wid * 16 * 32;
  unsigned short* lA1 = At  + (64 + wid * 16) * 32;
  unsigned short* lB0 = Btl + wid * 16 * 32;
  unsigned short* lB1 = Btl + (64 + wid * 16) * 32;

  for (int ks = 0; ks < K; ks += 32){
    load_lds16(a0 + ks, lA0);
    load_lds16(a1 + ks, lA1);
    load_lds16(b0 + ks, lB0);
    load_lds16(b1 + ks, lB1);
    __syncthreads();
    s8v af[4], bf[4];
    #pragma unroll
    for (int mc = 0; mc < 4; mc++){
      int row = wr * 64 + mc * 16 + l15;
      int o = (row * 64 + g * 16) ^ (((row >> 1) & 3) << 4);
      af[mc] = *(const s8v*)((const char*)At + o);
    }
    #pragma unroll
    for (int nc = 0; nc < 4; nc++){
      int row = wc * 64 + nc * 16 + l15;
      int o = (row * 64 + g * 16) ^ (((row >> 1) & 3) << 4);
      bf[nc] = *(const s8v*)((const char*)Btl + o);
    }
    #pragma unroll
    for (int mc = 0; mc < 4; mc++)
      #pragma unroll
      for (int nc = 0; nc < 4; nc++)
        acc[mc][nc] = mfma32(af[mc], bf[nc], acc[mc][nc]);
    __syncthreads();
  }

  if (MODE == 0){
    const int which = nbase / 768;
    const int head  = ((nbase % 768) >> 6) + wc;
    #pragma unroll
    for (int nc = 0; nc < 4; nc++){
      int j = nbase + wc * 64 + nc * 16 + l15;
      float bv = bias[j];
      int d = nc * 16 + l15;
      #pragma unroll
      for (int mc = 0; mc < 4; mc++){
        int m0 = mbase + wr * 64 + mc * 16 + g * 4;
        if (m0 >= M) continue;
        int b = m0 / 1032, n = m0 % 1032;
        int bh = b * 12 + head;
        if (which == 2){
          us4v pk = { f2bf(acc[mc][nc][0] + bv), f2bf(acc[mc][nc][1] + bv),
                      f2bf(acc[mc][nc][2] + bv), f2bf(acc[mc][nc][3] + bv) };
          *(us4v*)(vtb + ((int64_t)bh * 64 + d) * 1032 + n) = pk;
        } else {
          unsigned short* dst = (which == 0 ? qb : kb) + ((int64_t)bh * 1032 + n) * 64 + d;
          #pragma unroll
          for (int r = 0; r < 4; r++) dst[(int64_t)r * 64] = f2bf(acc[mc][nc][r] + bv);
        }
      }
    }
  } else {
    #pragma unroll
    for (int nc = 0; nc < 4; nc++){
      int j = nbase + wc * 64 + nc * 16 + l15;
      float bv = bias[j];
      #pragma unroll
      for (int mc = 0; mc < 4; mc++){
        int m0 = mbase + wr * 64 + mc * 16 + g * 4;
        if (m0 >= M) continue;
        int b = m0 / 1032, n0 = m0 % 1032;
        #pragma unroll
        for (int r = 0; r < 4; r++){
          int n = n0 + r;
          float v = acc[mc][nc][r] + bv;
          int64_t dst = (n < 8) ? (6291456LL + ((int64_t)(b * 8 + n)) * 768 + j)
                                : (((int64_t)(b * 1024 + (n - 8))) * 768 + j);
          outp[dst] = v;
        }
      }
    }
  }
}

// ---------------- rel_h: [bh][kh][qp] = q . Rh ----------------
__global__ __launch_bounds__(64) void k_rel_h(const unsigned short* __restrict__ qbuf,
    const float* __restrict__ rph, float* __restrict__ relh)
{
  const int lane = threadIdx.x;
  const int bh = blockIdx.x >> 5;
  const int qh = blockIdx.x & 31;
  const int g = lane >> 4, l15 = lane & 15;
  s8v qf[2][2];
  #pragma unroll
  for (int qc = 0; qc < 2; qc++){
    int n = qh * 32 + qc * 16 + l15 + 8;
    #pragma unroll
    for (int ch = 0; ch < 2; ch++)
      qf[qc][ch] = *(const s8v*)(qbuf + ((int64_t)bh * 1032 + n) * 64 + ch * 32 + g * 8);
  }
  s8v rf[2][2];
  #pragma unroll
  for (int kc = 0; kc < 2; kc++){
    int kh = kc * 16 + l15;
    #pragma unroll
    for (int ch = 0; ch < 2; ch++){
      const float* rp = rph + (int64_t)(qh - kh + 31) * 64 + ch * 32 + g * 8;
      f32x4v v0 = *(const f32x4v*)rp;
      f32x4v v1 = *(const f32x4v*)(rp + 4);
      s8v t = { (short)f2bf(v0[0]), (short)f2bf(v0[1]), (short)f2bf(v0[2]), (short)f2bf(v0[3]),
                (short)f2bf(v1[0]), (short)f2bf(v1[1]), (short)f2bf(v1[2]), (short)f2bf(v1[3]) };
      rf[kc][ch] = t;
    }
  }
  #pragma unroll
  for (int kc = 0; kc < 2; kc++)
    #pragma unroll
    for (int qc = 0; qc < 2; qc++){
      f4v d = {0.f, 0.f, 0.f, 0.f};
      d = mfma32(rf[kc][0], qf[qc][0], d);
      d = mfma32(rf[kc][1], qf[qc][1], d);
      #pragma unroll
      for (int r = 0; r < 4; r++)
        relh[((int64_t)bh * 32 + kc * 16 + g * 4 + r) * 1024 + qh * 32 + qc * 16 + l15] = d[r];
    }
}

// ---------------- rel_w: [bh][qp][kw] = q . Rw ----------------
__global__ __launch_bounds__(64) void k_rel_w(const unsigned short* __restrict__ qbuf,
    const float* __restrict__ rpw, float* __restrict__ relw)
{
  const int lane = threadIdx.x;
  const int bh = blockIdx.x >> 5;
  const int qw = blockIdx.x & 31;
  const int g = lane >> 4, l15 = lane & 15;
  s8v qf[2][2];
  #pragma unroll
  for (int qc = 0; qc < 2; qc++){
    int qp = qw + 32 * (qc * 16 + l15);
    int n = qp + 8;
    #pragma unroll
    for (int ch = 0; ch < 2; ch++)
      qf[qc][ch] = *(const s8v*)(qbuf + ((int64_t)bh * 1032 + n) * 64 + ch * 32 + g * 8);
  }
  s8v wf[2][2];
  #pragma unroll
  for (int kc = 0; kc < 2; kc++){
    int kw = kc * 16 + l15;
    #pragma unroll
    for (int ch = 0; ch < 2; ch++){
      const float* rp = rpw + (int64_t)(qw - kw + 31) * 64 + ch * 32 + g * 8;
      f32x4v v0 = *(const f32x4v*)rp;
      f32x4v v1 = *(const f32x4v*)(rp + 4);
      s8v t = { (short)f2bf(v0[0]), (short)f2bf(v0[1]), (short)f2bf(v0[2]), (short)f2bf(v0[3]),
                (short)f2bf(v1[0]), (short)f2bf(v1[1]), (short)f2bf(v1[2]), (short)f2bf(v1[3]) };
      wf[kc][ch] = t;
    }
  }
  #pragma unroll
  for (int qc = 0; qc < 2; qc++)
    #pragma unroll
    for (int kc = 0; kc < 2; kc++){
      f4v d = {0.f, 0.f, 0.f, 0.f};
      d = mfma32(qf[qc][0], wf[kc][0], d);
      d = mfma32(qf[qc][1], wf[kc][1], d);
      #pragma unroll
      for (int r = 0; r < 4; r++){
        int qp = qw + 32 * (qc * 16 + g * 4 + r);
        relw[((int64_t)bh * 1024 + qp) * 32 + kc * 16 + l15] = d[r];
      }
    }
}

// ---------------- flash attention with rel-pos bias ----------------
__global__ __launch_bounds__(256) void k_attn(
    const unsigned short* __restrict__ qb, const unsigned short* __restrict__ kb,
    const unsigned short* __restrict__ vtb, const float* __restrict__ relh,
    const float* __restrict__ relw, unsigned short* __restrict__ ao)
{
  const int lane = threadIdx.x & 63, wid = threadIdx.x >> 6;
  const int bh = blockIdx.x / 9;
  const int qt = (blockIdx.x % 9) * 4 + wid;
  if (qt >= 33) return;
  const int qbase = qt * 32;
  const int g = lane >> 4, l15 = lane & 15;
  const int b = bh / 12, head = bh % 12;

  s8v qf[2][2];
  int qn_[2], qp_[2];
  #pragma unroll
  for (int qc = 0; qc < 2; qc++){
    int qn = qbase + qc * 16 + l15;
    qn_[qc] = qn;
    int qcl = qn < 1032 ? qn : 1031;
    #pragma unroll
    for (int ch = 0; ch < 2; ch++)
      qf[qc][ch] = *(const s8v*)(qb + ((int64_t)bh * 1032 + qcl) * 64 + ch * 32 + g * 8);
    int qp = qn - 8; if (qp < 0) qp = 0; if (qp > 1023) qp = 1023;
    qp_[qc] = qp;
  }
  float rw[2][2][4];
  #pragma unroll
  for (int qc = 0; qc < 2; qc++)
    #pragma unroll
    for (int kc = 0; kc < 2; kc++)
      #pragma unroll
      for (int r = 0; r < 4; r++){
        int kw = (kc * 16 + g * 4 + r + 24) & 31;
        rw[qc][kc][r] = relw[((int64_t)bh * 1024 + qp_[qc]) * 32 + kw];
      }

  f4v of[4][2] = {};
  float mrun[2] = {-3.0e38f, -3.0e38f};
  float lrun[2] = {0.f, 0.f};

  for (int kt = 0; kt < 33; kt++){
    s8v kf[2][2];
    #pragma unroll
    for (int kc = 0; kc < 2; kc++){
      int key = kt * 32 + kc * 16 + l15; if (key > 1031) key = 1031;
      #pragma unroll
      for (int ch = 0; ch < 2; ch++)
        kf[kc][ch] = *(const s8v*)(kb + ((int64_t)bh * 1032 + key) * 64 + ch * 32 + g * 8);
    }
    int khA = kt - 1; if (khA < 0) khA = 0;
    int khB = kt; if (khB > 31) khB = 31;
    float rhA[2], rhB[2];
    #pragma unroll
    for (int qc = 0; qc < 2; qc++){
      rhA[qc] = relh[((int64_t)bh * 32 + khA) * 1024 + qp_[qc]];
      rhB[qc] = relh[((int64_t)bh * 32 + khB) * 1024 + qp_[qc]];
    }
    float pc[2][2][4];
    #pragma unroll
    for (int qc = 0; qc < 2; qc++){
      bool qpr = qn_[qc] < 8;
      #pragma unroll
      for (int kc = 0; kc < 2; kc++){
        f4v s = {0.f, 0.f, 0.f, 0.f};
        s = mfma32(kf[kc][0], qf[qc][0], s);
        s = mfma32(kf[kc][1], qf[qc][1], s);
        #pragma unroll
        for (int r = 0; r < 4; r++){
          int off = kc * 16 + g * 4 + r;
          int key = kt * 32 + off;
          float L = s[r] * 0.125f;
          if (key >= 1032) L = -3.0e38f;
          else if (!qpr) L += (key < 8) ? -100.0f : ((off >= 8 ? rhB[qc] : rhA[qc]) + rw[qc][kc][r]);
          pc[qc][kc][r] = L;
        }
      }
    }
    s4v bp[2][2];
    #pragma unroll
    for (int qc = 0; qc < 2; qc++){
      float tm = -3.0e38f;
      #pragma unroll
      for (int kc = 0; kc < 2; kc++)
        #pragma unroll
        for (int r = 0; r < 4; r++) tm = fmaxf(tm, pc[qc][kc][r]);
      tm = fmaxf(tm, __shfl_xor(tm, 16));
      tm = fmaxf(tm, __shfl_xor(tm, 32));
      float mnew = fmaxf(mrun[qc], tm);
      float alpha = __expf(mrun[qc] - mnew);
      mrun[qc] = mnew;
      float ssum = 0.f;
      #pragma unroll
      for (int kc = 0; kc < 2; kc++)
        #pragma unroll
        for (int r = 0; r < 4; r++){
          float p = __expf(pc[qc][kc][r] - mnew);
          pc[qc][kc][r] = p;
          ssum += p;
        }
      ssum += __shfl_xor(ssum, 16);
      ssum += __shfl_xor(ssum, 32);
      lrun[qc] = lrun[qc] * alpha + ssum;
      #pragma unroll
      for (int dc = 0; dc < 4; dc++)
        of[dc][qc] = of[dc][qc] * alpha;
      s4v t = { (short)f2bf(pc[qc][0][0]), (short)f2bf(pc[qc][0][1]),
                (short)f2bf(pc[qc][0][2]), (short)f2bf(pc[qc][0][3]) };
      bp[qc][0] = t;
      s4v t2 = { (short)f2bf(pc[qc][1][0]), (short)f2bf(pc[qc][1][1]),
                 (short)f2bf(pc[qc][1][2]), (short)f2bf(pc[qc][1][3]) };
      bp[qc][1] = t2;
    }
    #pragma unroll
    for (int dc = 0; dc < 4; dc++){
      int d = dc * 16 + l15;
      const unsigned short* vrow = vtb + ((int64_t)bh * 64 + d) * 1032;
      #pragma unroll
      for (int kc = 0; kc < 2; kc++){
        s4v vf = *(const s4v*)(vrow + kt * 32 + kc * 16 + g * 4);
        #pragma unroll
        for (int qc = 0; qc < 2; qc++)
          of[dc][qc] = mfma16(vf, bp[qc][kc], of[dc][qc]);
      }
    }
  }

  #pragma unroll
  for (int qc = 0; qc < 2; qc++){
    int qn = qn_[qc];
    if (qn >= 1032) continue;
    float inv = 1.0f / lrun[qc];
    unsigned short* dst = ao + ((int64_t)(b * 1032 + qn)) * 768 + head * 64;
    #pragma unroll
    for (int dc = 0; dc < 4; dc++){
      us4v pk = { f2bf(of[dc][qc][0] * inv), f2bf(of[dc][qc][1] * inv),
                  f2bf(of[dc][qc][2] * inv), f2bf(of[dc][qc][3] * inv) };
      *(us4v*)(dst + dc * 16 + g * 4) = pk;
    }
  }
}

extern "C" void kernel_launch(void* const* d_in, const int* in_sizes, int n_in,
                              void* d_out, int out_size, void* d_ws, size_t ws_size,
                              hipStream_t stream)
{
  const float* x   = (const float*)d_in[0];
  const float* vp  = (const float*)d_in[1];
  const float* qw  = (const float*)d_in[2];
  const float* qbb = (const float*)d_in[3];
  const float* pw  = (const float*)d_in[4];
  const float* pb  = (const float*)d_in[5];
  const float* rph = (const float*)d_in[6];
  const float* rpw = (const float*)d_in[7];
  float* out = (float*)d_out;

  char* ws = (char*)d_ws;
  size_t off = 0;
  auto alloc = [&](size_t bytes) -> void* {
    void* p = ws + off;
    off = (off + bytes + 255) & ~(size_t)255;
    return p;
  };
  unsigned short* xs   = (unsigned short*)alloc((size_t)8256 * 768 * 2);
  unsigned short* Wt   = (unsigned short*)alloc((size_t)2304 * 768 * 2);
  unsigned short* Pt   = (unsigned short*)alloc((size_t)768 * 768 * 2);
  unsigned short* qbuf = (unsigned short*)alloc((size_t)96 * 1032 * 64 * 2);
  unsigned short* kbuf = (unsigned short*)alloc((size_t)96 * 1032 * 64 * 2);
  unsigned short* vtb  = (unsigned short*)alloc((size_t)96 * 64 * 1032 * 2 + 256);
  float* relh = (float*)alloc((size_t)96 * 32 * 1024 * 4);
  float* relw = (float*)alloc((size_t)96 * 1024 * 32 * 4);
  unsigned short* ao = xs;  // xs is dead after the QKV GEMM; reuse for attention output

  k_prep_xs<<<6192, 256, 0, stream>>>(x, vp, xs);
  k_prep_w<<<9216, 256, 0, stream>>>(qw, pw, Wt, Pt);
  k_gemm<0><<<dim3(18, 65), 256, 0, stream>>>(xs, Wt, qbb, 8256, 2304, 768,
                                              qbuf, kbuf, vtb, nullptr);
  k_rel_h<<<3072, 64, 0, stream>>>(qbuf, rph, relh);
  k_rel_w<<<3072, 64, 0, stream>>>(qbuf, rpw, relw);
  k_attn<<<864, 256, 0, stream>>>(qbuf, kbuf, vtb, relh, relw, ao);
  k_gemm<1><<<dim3(6, 65), 256, 0, stream>>>(ao, Pt, pb, 8256, 768, 768,
                                             nullptr, nullptr, nullptr, out);
}

// Round 2
// 233.395 us; speedup vs baseline: 1.0909x; 1.0909x over previous
//
#include <hip/hip_runtime.h>
#include <stdint.h>

typedef __attribute__((ext_vector_type(8))) short s8v;
typedef __attribute__((ext_vector_type(4))) short s4v;
typedef __attribute__((ext_vector_type(4))) float f4v;
typedef __attribute__((ext_vector_type(4))) unsigned short us4v;
typedef __attribute__((ext_vector_type(4))) float f32x4v;

#define DEV static __device__ __forceinline__

#define L2E 1.44269504f

DEV unsigned short f2bf(float f){
  uint32_t x = __builtin_bit_cast(uint32_t, f);
  uint32_t r = x + 0x7fffu + ((x >> 16) & 1u);
  return (unsigned short)(r >> 16);
}

DEV float exp2g(float x){
#if __has_builtin(__builtin_amdgcn_exp2f)
  return __builtin_amdgcn_exp2f(x);
#else
  return exp2f(x);
#endif
}

DEV f4v mfma32(s8v a, s8v b, f4v c){
  return __builtin_amdgcn_mfma_f32_16x16x32_bf16(a, b, c, 0, 0, 0);
}
DEV f4v mfma16(s4v a, s4v b, f4v c){
  return __builtin_amdgcn_mfma_f32_16x16x16bf16_1k(a, b, c, 0, 0, 0);
}

DEV void load_lds16(const void* g, void* l){
  __builtin_amdgcn_global_load_lds((const __attribute__((address_space(1))) uint32_t*)g,
                                   (__attribute__((address_space(3))) uint32_t*)l, 16, 0, 0);
}

// ---------------- prep: xs = concat(vp, x) -> bf16 ----------------
__global__ void k_prep_xs(const float* __restrict__ x, const float* __restrict__ vp,
                          unsigned short* __restrict__ xs){
  int64_t e = ((int64_t)blockIdx.x * 256 + threadIdx.x) * 4;
  int m = (int)(e / 768); int c = (int)(e % 768);
  int b = m / 1032, n = m % 1032;
  const float* src = (n < 8) ? (vp + ((int64_t)(b * 8 + n)) * 768 + c)
                             : (x  + ((int64_t)(b * 1024 + (n - 8))) * 768 + c);
  f32x4v v = *(const f32x4v*)src;
  us4v o = { f2bf(v[0]), f2bf(v[1]), f2bf(v[2]), f2bf(v[3]) };
  *(us4v*)(xs + e) = o;
}

// ---------------- prep: W transposes -> bf16 ----------------
__global__ void k_prep_w(const float* __restrict__ qw, const float* __restrict__ pw,
                         unsigned short* __restrict__ Wt, unsigned short* __restrict__ Pt){
  int64_t idx = (int64_t)blockIdx.x * 256 + threadIdx.x;
  if (idx < (int64_t)2304 * 768){
    int j = (int)(idx / 768), k = (int)(idx % 768);
    Wt[idx] = f2bf(qw[(int64_t)k * 2304 + j]);
  } else {
    int64_t t = idx - (int64_t)2304 * 768;
    if (t < (int64_t)768 * 768){
      int j = (int)(t / 768), k = (int)(t % 768);
      Pt[t] = f2bf(pw[(int64_t)k * 768 + j]);
    }
  }
}

// ---------------- GEMM: C = A[M,K] * Bt[N,K]^T + bias ----------------
template<int MODE>
__global__ __launch_bounds__(256) void k_gemm(
    const unsigned short* __restrict__ A, const unsigned short* __restrict__ Bt,
    const float* __restrict__ bias, int M, int N, int K,
    unsigned short* __restrict__ qb, unsigned short* __restrict__ kb,
    unsigned short* __restrict__ vtb, float* __restrict__ outp)
{
  __shared__ __align__(16) unsigned short At [128 * 32];
  __shared__ __align__(16) unsigned short Btl[128 * 32];
  const int tid = threadIdx.x, lane = tid & 63, wid = tid >> 6;
  const int mbase = blockIdx.y * 128, nbase = blockIdx.x * 128;
  const int wr = wid >> 1, wc = wid & 1;
  const int g = lane >> 4, l15 = lane & 15;
  const int l2 = lane >> 2, l3 = lane & 3;
  f4v acc[4][4] = {};

  int srow0 = wid * 16 + l2;
  int srow1 = 64 + wid * 16 + l2;
  int sg0 = l3 ^ ((srow0 >> 1) & 3);
  int sg1 = l3 ^ ((srow1 >> 1) & 3);
  int arow0 = mbase + srow0; if (arow0 >= M) arow0 = 0;
  int arow1 = mbase + srow1; if (arow1 >= M) arow1 = 0;
  const unsigned short* a0 = A  + (int64_t)arow0 * K + sg0 * 8;
  const unsigned short* a1 = A  + (int64_t)arow1 * K + sg1 * 8;
  const unsigned short* b0 = Bt + (int64_t)(nbase + srow0) * K + sg0 * 8;
  const unsigned short* b1 = Bt + (int64_t)(nbase + srow1) * K + sg1 * 8;
  unsigned short* lA0 = At  + wid * 16 * 32;
  unsigned short* lA1 = At  + (64 + wid * 16) * 32;
  unsigned short* lB0 = Btl + wid * 16 * 32;
  unsigned short* lB1 = Btl + (64 + wid * 16) * 32;

  for (int ks = 0; ks < K; ks += 32){
    load_lds16(a0 + ks, lA0);
    load_lds16(a1 + ks, lA1);
    load_lds16(b0 + ks, lB0);
    load_lds16(b1 + ks, lB1);
    __syncthreads();
    s8v af[4], bf[4];
    #pragma unroll
    for (int mc = 0; mc < 4; mc++){
      int row = wr * 64 + mc * 16 + l15;
      int o = (row * 64 + g * 16) ^ (((row >> 1) & 3) << 4);
      af[mc] = *(const s8v*)((const char*)At + o);
    }
    #pragma unroll
    for (int nc = 0; nc < 4; nc++){
      int row = wc * 64 + nc * 16 + l15;
      int o = (row * 64 + g * 16) ^ (((row >> 1) & 3) << 4);
      bf[nc] = *(const s8v*)((const char*)Btl + o);
    }
    #pragma unroll
    for (int mc = 0; mc < 4; mc++)
      #pragma unroll
      for (int nc = 0; nc < 4; nc++)
        acc[mc][nc] = mfma32(af[mc], bf[nc], acc[mc][nc]);
    __syncthreads();
  }

  if (MODE == 0){
    const int which = nbase / 768;
    const int head  = ((nbase % 768) >> 6) + wc;
    #pragma unroll
    for (int nc = 0; nc < 4; nc++){
      int j = nbase + wc * 64 + nc * 16 + l15;
      float bv = bias[j];
      int d = nc * 16 + l15;
      #pragma unroll
      for (int mc = 0; mc < 4; mc++){
        int m0 = mbase + wr * 64 + mc * 16 + g * 4;
        if (m0 >= M) continue;
        int b = m0 / 1032, n = m0 % 1032;
        int bh = b * 12 + head;
        if (which == 2){
          us4v pk = { f2bf(acc[mc][nc][0] + bv), f2bf(acc[mc][nc][1] + bv),
                      f2bf(acc[mc][nc][2] + bv), f2bf(acc[mc][nc][3] + bv) };
          *(us4v*)(vtb + ((int64_t)bh * 64 + d) * 1032 + n) = pk;
        } else {
          unsigned short* dst = (which == 0 ? qb : kb) + ((int64_t)bh * 1032 + n) * 64 + d;
          #pragma unroll
          for (int r = 0; r < 4; r++) dst[(int64_t)r * 64] = f2bf(acc[mc][nc][r] + bv);
        }
      }
    }
  } else {
    #pragma unroll
    for (int nc = 0; nc < 4; nc++){
      int j = nbase + wc * 64 + nc * 16 + l15;
      float bv = bias[j];
      #pragma unroll
      for (int mc = 0; mc < 4; mc++){
        int m0 = mbase + wr * 64 + mc * 16 + g * 4;
        if (m0 >= M) continue;
        int b = m0 / 1032, n0 = m0 % 1032;
        #pragma unroll
        for (int r = 0; r < 4; r++){
          int n = n0 + r;
          float v = acc[mc][nc][r] + bv;
          int64_t dst = (n < 8) ? (6291456LL + ((int64_t)(b * 8 + n)) * 768 + j)
                                : (((int64_t)(b * 1024 + (n - 8))) * 768 + j);
          outp[dst] = v;
        }
      }
    }
  }
}

// ---------------- rel_h: [bh][kh][qp] = (q . Rh) * log2e ----------------
__global__ __launch_bounds__(64) void k_rel_h(const unsigned short* __restrict__ qbuf,
    const float* __restrict__ rph, float* __restrict__ relh)
{
  const int lane = threadIdx.x;
  const int bh = blockIdx.x >> 5;
  const int qh = blockIdx.x & 31;
  const int g = lane >> 4, l15 = lane & 15;
  s8v qf[2][2];
  #pragma unroll
  for (int qc = 0; qc < 2; qc++){
    int n = qh * 32 + qc * 16 + l15 + 8;
    #pragma unroll
    for (int ch = 0; ch < 2; ch++)
      qf[qc][ch] = *(const s8v*)(qbuf + ((int64_t)bh * 1032 + n) * 64 + ch * 32 + g * 8);
  }
  s8v rf[2][2];
  #pragma unroll
  for (int kc = 0; kc < 2; kc++){
    int kh = kc * 16 + l15;
    #pragma unroll
    for (int ch = 0; ch < 2; ch++){
      const float* rp = rph + (int64_t)(qh - kh + 31) * 64 + ch * 32 + g * 8;
      f32x4v v0 = *(const f32x4v*)rp;
      f32x4v v1 = *(const f32x4v*)(rp + 4);
      s8v t = { (short)f2bf(v0[0]), (short)f2bf(v0[1]), (short)f2bf(v0[2]), (short)f2bf(v0[3]),
                (short)f2bf(v1[0]), (short)f2bf(v1[1]), (short)f2bf(v1[2]), (short)f2bf(v1[3]) };
      rf[kc][ch] = t;
    }
  }
  #pragma unroll
  for (int kc = 0; kc < 2; kc++)
    #pragma unroll
    for (int qc = 0; qc < 2; qc++){
      f4v d = {0.f, 0.f, 0.f, 0.f};
      d = mfma32(rf[kc][0], qf[qc][0], d);
      d = mfma32(rf[kc][1], qf[qc][1], d);
      #pragma unroll
      for (int r = 0; r < 4; r++)
        relh[((int64_t)bh * 32 + kc * 16 + g * 4 + r) * 1024 + qh * 32 + qc * 16 + l15] = d[r] * L2E;
    }
}

// ---------------- rel_w: [bh][qp][kw] = (q . Rw) * log2e ----------------
__global__ __launch_bounds__(64) void k_rel_w(const unsigned short* __restrict__ qbuf,
    const float* __restrict__ rpw, float* __restrict__ relw)
{
  const int lane = threadIdx.x;
  const int bh = blockIdx.x >> 5;
  const int qw = blockIdx.x & 31;
  const int g = lane >> 4, l15 = lane & 15;
  s8v qf[2][2];
  #pragma unroll
  for (int qc = 0; qc < 2; qc++){
    int qp = qw + 32 * (qc * 16 + l15);
    int n = qp + 8;
    #pragma unroll
    for (int ch = 0; ch < 2; ch++)
      qf[qc][ch] = *(const s8v*)(qbuf + ((int64_t)bh * 1032 + n) * 64 + ch * 32 + g * 8);
  }
  s8v wf[2][2];
  #pragma unroll
  for (int kc = 0; kc < 2; kc++){
    int kw = kc * 16 + l15;
    #pragma unroll
    for (int ch = 0; ch < 2; ch++){
      const float* rp = rpw + (int64_t)(qw - kw + 31) * 64 + ch * 32 + g * 8;
      f32x4v v0 = *(const f32x4v*)rp;
      f32x4v v1 = *(const f32x4v*)(rp + 4);
      s8v t = { (short)f2bf(v0[0]), (short)f2bf(v0[1]), (short)f2bf(v0[2]), (short)f2bf(v0[3]),
                (short)f2bf(v1[0]), (short)f2bf(v1[1]), (short)f2bf(v1[2]), (short)f2bf(v1[3]) };
      wf[kc][ch] = t;
    }
  }
  #pragma unroll
  for (int qc = 0; qc < 2; qc++)
    #pragma unroll
    for (int kc = 0; kc < 2; kc++){
      f4v d = {0.f, 0.f, 0.f, 0.f};
      d = mfma32(qf[qc][0], wf[kc][0], d);
      d = mfma32(qf[qc][1], wf[kc][1], d);
      #pragma unroll
      for (int r = 0; r < 4; r++){
        int qp = qw + 32 * (qc * 16 + g * 4 + r);
        relw[((int64_t)bh * 1024 + qp) * 32 + kc * 16 + l15] = d[r] * L2E;
      }
    }
}

// ---------------- flash attention, K-dim split 2x + LDS merge ----------------
// Block: 256 threads = 4 waves = 2 q-tiles x 2 key-halves.
// Wave (qt_local, h) processes q-tile qt = qtg*2+qt_local over k-tiles
// [0..16] (h=0) or [17..32] (h=1); h=1 writes partial (m,l,O) to LDS and
// h=0 merges + stores. Softmax in exp2 domain (relh/relw pre-scaled by log2e).
__global__ __launch_bounds__(256, 4) void k_attn(
    const unsigned short* __restrict__ qb, const unsigned short* __restrict__ kb,
    const unsigned short* __restrict__ vtb, const float* __restrict__ relh,
    const float* __restrict__ relw, unsigned short* __restrict__ ao)
{
  const int lane = threadIdx.x & 63, wid = threadIdx.x >> 6;
  const int bh = blockIdx.x / 17;
  const int qtg = blockIdx.x % 17;
  const int qtl = wid >> 1;
  const int h = wid & 1;
  const int qt = qtg * 2 + qtl;
  const bool valid = (qt < 33);
  const int qbase = qt * 32;
  const int g = lane >> 4, l15 = lane & 15;
  const int b = bh / 12, head = bh % 12;
  const float C1 = 0.125f * L2E;

  __shared__ __align__(16) float ofs[2][4][2][64][4];
  __shared__ float mls[2][2][64][2];

  f4v of[4][2] = {};
  float mrun[2] = {-3.0e38f, -3.0e38f};
  float lrun[2] = {0.f, 0.f};
  int qn_[2], qp_[2];

  if (valid){
    s8v qf[2][2];
    float rw[2][2][4];
    #pragma unroll
    for (int qc = 0; qc < 2; qc++){
      int qn = qbase + qc * 16 + l15;
      qn_[qc] = qn;
      int qcl = qn < 1032 ? qn : 1031;
      #pragma unroll
      for (int ch = 0; ch < 2; ch++)
        qf[qc][ch] = *(const s8v*)(qb + ((int64_t)bh * 1032 + qcl) * 64 + ch * 32 + g * 8);
      int qp = qn - 8; if (qp < 0) qp = 0; if (qp > 1023) qp = 1023;
      qp_[qc] = qp;
    }
    #pragma unroll
    for (int qc = 0; qc < 2; qc++)
      #pragma unroll
      for (int kc = 0; kc < 2; kc++)
        #pragma unroll
        for (int r = 0; r < 4; r++){
          int kw = (kc * 16 + g * 4 + r + 24) & 31;
          rw[qc][kc][r] = relw[((int64_t)bh * 1024 + qp_[qc]) * 32 + kw];
        }

    const unsigned short* vbase = vtb + (int64_t)bh * 64 * 1032;
    const int kt_lo = h ? 17 : 0;
    const int kt_hi = h ? 33 : 17;

    for (int kt = kt_lo; kt < kt_hi; kt++){
      // K fragments
      s8v kf[2][2];
      #pragma unroll
      for (int kc = 0; kc < 2; kc++){
        int key = kt * 32 + kc * 16 + l15; if (key > 1031) key = 1031;
        #pragma unroll
        for (int ch = 0; ch < 2; ch++)
          kf[kc][ch] = *(const s8v*)(kb + ((int64_t)bh * 1032 + key) * 64 + ch * 32 + g * 8);
      }
      // QK^T (swapped -> lane col = query)
      f4v sv[2][2];
      #pragma unroll
      for (int qc = 0; qc < 2; qc++)
        #pragma unroll
        for (int kc = 0; kc < 2; kc++){
          f4v s = {0.f, 0.f, 0.f, 0.f};
          s = mfma32(kf[kc][0], qf[qc][0], s);
          s = mfma32(kf[kc][1], qf[qc][1], s);
          sv[qc][kc] = s;
        }
      // V fragments early (latency hidden under softmax VALU)
      s4v vf[4][2];
      #pragma unroll
      for (int dc = 0; dc < 4; dc++)
        #pragma unroll
        for (int kc = 0; kc < 2; kc++)
          vf[dc][kc] = *(const s4v*)(vbase + (int64_t)(dc * 16 + l15) * 1032 + kt * 32 + kc * 16 + g * 4);
      // rel_h values for this k-tile
      int khA = kt - 1; if (khA < 0) khA = 0;
      int khB = kt; if (khB > 31) khB = 31;
      float rhA[2], rhB[2];
      #pragma unroll
      for (int qc = 0; qc < 2; qc++){
        rhA[qc] = relh[((int64_t)bh * 32 + khA) * 1024 + qp_[qc]];
        rhB[qc] = relh[((int64_t)bh * 32 + khB) * 1024 + qp_[qc]];
      }
      const bool anyprompt = (kt == 0);
      const bool anymask = (kt == 32);
      s4v bp[2][2];
      #pragma unroll
      for (int qc = 0; qc < 2; qc++){
        const bool qpr = qn_[qc] < 8;
        float pc[2][4];
        #pragma unroll
        for (int kc = 0; kc < 2; kc++)
          #pragma unroll
          for (int r = 0; r < 4; r++){
            int off = kc * 16 + g * 4 + r;
            float bias = qpr ? 0.f : ((off >= 8 ? rhB[qc] : rhA[qc]) + rw[qc][kc][r]);
            if (anyprompt && off < 8 && !qpr) bias = -144.269504f;
            float L = fmaf(sv[qc][kc][r], C1, bias);
            if (anymask && off >= 8) L = -3.0e38f;
            pc[kc][r] = L;
          }
        // per-query max over 8 local + cross-g
        float tm = fmaxf(fmaxf(fmaxf(pc[0][0], pc[0][1]), fmaxf(pc[0][2], pc[0][3])),
                         fmaxf(fmaxf(pc[1][0], pc[1][1]), fmaxf(pc[1][2], pc[1][3])));
        tm = fmaxf(tm, __shfl_xor(tm, 16));
        tm = fmaxf(tm, __shfl_xor(tm, 32));
        if (!__all(tm <= mrun[qc])){
          float mnew = fmaxf(mrun[qc], tm);
          float alpha = exp2g(mrun[qc] - mnew);
          mrun[qc] = mnew;
          lrun[qc] *= alpha;
          #pragma unroll
          for (int dc = 0; dc < 4; dc++)
            of[dc][qc] = of[dc][qc] * alpha;
        }
        float m = mrun[qc];
        float ssum = 0.f;
        #pragma unroll
        for (int kc = 0; kc < 2; kc++)
          #pragma unroll
          for (int r = 0; r < 4; r++){
            float p = exp2g(pc[kc][r] - m);
            pc[kc][r] = p;
            ssum += p;
          }
        ssum += __shfl_xor(ssum, 16);
        ssum += __shfl_xor(ssum, 32);
        lrun[qc] += ssum;
        s4v t0 = { (short)f2bf(pc[0][0]), (short)f2bf(pc[0][1]),
                   (short)f2bf(pc[0][2]), (short)f2bf(pc[0][3]) };
        bp[qc][0] = t0;
        s4v t1 = { (short)f2bf(pc[1][0]), (short)f2bf(pc[1][1]),
                   (short)f2bf(pc[1][2]), (short)f2bf(pc[1][3]) };
        bp[qc][1] = t1;
      }
      // PV
      #pragma unroll
      for (int dc = 0; dc < 4; dc++)
        #pragma unroll
        for (int kc = 0; kc < 2; kc++)
          #pragma unroll
          for (int qc = 0; qc < 2; qc++)
            of[dc][qc] = mfma16(vf[dc][kc], bp[qc][kc], of[dc][qc]);
    }
  }

  // publish h=1 partials
  if (valid && h == 1){
    #pragma unroll
    for (int dc = 0; dc < 4; dc++)
      #pragma unroll
      for (int qc = 0; qc < 2; qc++)
        *(f4v*)&ofs[qtl][dc][qc][lane][0] = of[dc][qc];
    #pragma unroll
    for (int qc = 0; qc < 2; qc++){
      mls[qtl][qc][lane][0] = mrun[qc];
      mls[qtl][qc][lane][1] = lrun[qc];
    }
  }
  __syncthreads();
  if (valid && h == 0){
    #pragma unroll
    for (int qc = 0; qc < 2; qc++){
      int qn = qn_[qc];
      if (qn >= 1032) continue;
      float m1 = mls[qtl][qc][lane][0];
      float l1 = mls[qtl][qc][lane][1];
      float M = fmaxf(mrun[qc], m1);
      float a0 = exp2g(mrun[qc] - M);
      float a1 = exp2g(m1 - M);
      float inv = 1.0f / (lrun[qc] * a0 + l1 * a1);
      float s0 = a0 * inv, s1 = a1 * inv;
      unsigned short* dst = ao + ((int64_t)(b * 1032 + qn)) * 768 + head * 64;
      #pragma unroll
      for (int dc = 0; dc < 4; dc++){
        f4v o1 = *(const f4v*)&ofs[qtl][dc][qc][lane][0];
        f4v om = of[dc][qc] * s0 + o1 * s1;
        us4v pk = { f2bf(om[0]), f2bf(om[1]), f2bf(om[2]), f2bf(om[3]) };
        *(us4v*)(dst + dc * 16 + g * 4) = pk;
      }
    }
  }
}

extern "C" void kernel_launch(void* const* d_in, const int* in_sizes, int n_in,
                              void* d_out, int out_size, void* d_ws, size_t ws_size,
                              hipStream_t stream)
{
  const float* x   = (const float*)d_in[0];
  const float* vp  = (const float*)d_in[1];
  const float* qw  = (const float*)d_in[2];
  const float* qbb = (const float*)d_in[3];
  const float* pw  = (const float*)d_in[4];
  const float* pb  = (const float*)d_in[5];
  const float* rph = (const float*)d_in[6];
  const float* rpw = (const float*)d_in[7];
  float* out = (float*)d_out;

  char* ws = (char*)d_ws;
  size_t off = 0;
  auto alloc = [&](size_t bytes) -> void* {
    void* p = ws + off;
    off = (off + bytes + 255) & ~(size_t)255;
    return p;
  };
  unsigned short* xs   = (unsigned short*)alloc((size_t)8256 * 768 * 2);
  unsigned short* Wt   = (unsigned short*)alloc((size_t)2304 * 768 * 2);
  unsigned short* Pt   = (unsigned short*)alloc((size_t)768 * 768 * 2);
  unsigned short* qbuf = (unsigned short*)alloc((size_t)96 * 1032 * 64 * 2);
  unsigned short* kbuf = (unsigned short*)alloc((size_t)96 * 1032 * 64 * 2);
  unsigned short* vtb  = (unsigned short*)alloc((size_t)96 * 64 * 1032 * 2 + 256);
  float* relh = (float*)alloc((size_t)96 * 32 * 1024 * 4);
  float* relw = (float*)alloc((size_t)96 * 1024 * 32 * 4);
  unsigned short* ao = xs;  // xs dead after QKV GEMM; reuse for attention output

  k_prep_xs<<<6192, 256, 0, stream>>>(x, vp, xs);
  k_prep_w<<<9216, 256, 0, stream>>>(qw, pw, Wt, Pt);
  k_gemm<0><<<dim3(18, 65), 256, 0, stream>>>(xs, Wt, qbb, 8256, 2304, 768,
                                              qbuf, kbuf, vtb, nullptr);
  k_rel_h<<<3072, 64, 0, stream>>>(qbuf, rph, relh);
  k_rel_w<<<3072, 64, 0, stream>>>(qbuf, rpw, relw);
  k_attn<<<1632, 256, 0, stream>>>(qbuf, kbuf, vtb, relh, relw, ao);
  k_gemm<1><<<dim3(6, 65), 256, 0, stream>>>(ao, Pt, pb, 8256, 768, 768,
                                             nullptr, nullptr, nullptr, out);
}

// Round 4
// 233.020 us; speedup vs baseline: 1.0927x; 1.0016x over previous
//
#include <hip/hip_runtime.h>
#include <stdint.h>

typedef __attribute__((ext_vector_type(8))) short s8v;
typedef __attribute__((ext_vector_type(4))) short s4v;
typedef __attribute__((ext_vector_type(4))) float f4v;
typedef __attribute__((ext_vector_type(4))) unsigned short us4v;
typedef __attribute__((ext_vector_type(4))) float f32x4v;

#define DEV static __device__ __forceinline__

#define L2E 1.44269504f

DEV unsigned short f2bf(float f){
  uint32_t x = __builtin_bit_cast(uint32_t, f);
  uint32_t r = x + 0x7fffu + ((x >> 16) & 1u);
  return (unsigned short)(r >> 16);
}

DEV float exp2g(float x){
#if __has_builtin(__builtin_amdgcn_exp2f)
  return __builtin_amdgcn_exp2f(x);
#else
  return exp2f(x);
#endif
}

// pack 4 f32 -> 4 bf16 (two v_cvt_pk_bf16_f32, RNE — same as f2bf)
DEV s4v pack4(float a, float b, float c, float d){
  uint32_t r0, r1;
  asm("v_cvt_pk_bf16_f32 %0, %1, %2" : "=v"(r0) : "v"(a), "v"(b));
  asm("v_cvt_pk_bf16_f32 %0, %1, %2" : "=v"(r1) : "v"(c), "v"(d));
  union { uint32_t u[2]; s4v s; } u; u.u[0] = r0; u.u[1] = r1; return u.s;
}

DEV f4v mfma32(s8v a, s8v b, f4v c){
  return __builtin_amdgcn_mfma_f32_16x16x32_bf16(a, b, c, 0, 0, 0);
}
DEV f4v mfma16(s4v a, s4v b, f4v c){
  return __builtin_amdgcn_mfma_f32_16x16x16bf16_1k(a, b, c, 0, 0, 0);
}

DEV void load_lds16(const void* g, void* l){
  __builtin_amdgcn_global_load_lds((const __attribute__((address_space(1))) uint32_t*)g,
                                   (__attribute__((address_space(3))) uint32_t*)l, 16, 0, 0);
}

// ---------------- prep: xs = concat(vp, x) -> bf16 ----------------
__global__ void k_prep_xs(const float* __restrict__ x, const float* __restrict__ vp,
                          unsigned short* __restrict__ xs){
  int64_t e = ((int64_t)blockIdx.x * 256 + threadIdx.x) * 4;
  int m = (int)(e / 768); int c = (int)(e % 768);
  int b = m / 1032, n = m % 1032;
  const float* src = (n < 8) ? (vp + ((int64_t)(b * 8 + n)) * 768 + c)
                             : (x  + ((int64_t)(b * 1024 + (n - 8))) * 768 + c);
  f32x4v v = *(const f32x4v*)src;
  us4v o = { f2bf(v[0]), f2bf(v[1]), f2bf(v[2]), f2bf(v[3]) };
  *(us4v*)(xs + e) = o;
}

// ---------------- prep: W transposes -> bf16 (LDS tile transpose) ----------------
// qw [768][2304] -> Wt [2304][768]; pw [768][768] -> Pt [768][768]
__global__ __launch_bounds__(256) void k_prep_w(const float* __restrict__ qw,
    const float* __restrict__ pw, unsigned short* __restrict__ Wt,
    unsigned short* __restrict__ Pt){
  __shared__ float tile[32][33];
  const int bid = blockIdx.x;
  const float* src; unsigned short* dst; int Cc, j0, k0;
  if (bid < 1728){
    int jt = bid % 72, kt = bid / 72;
    src = qw; dst = Wt; Cc = 2304; k0 = kt * 32; j0 = jt * 32;
  } else {
    int t2 = bid - 1728;
    int jt = t2 % 24, kt = t2 / 24;
    src = pw; dst = Pt; Cc = 768; k0 = kt * 32; j0 = jt * 32;
  }
  const int t = threadIdx.x;
  const int r = t >> 3, c4 = (t & 7) * 4;
  f32x4v v = *(const f32x4v*)(src + (int64_t)(k0 + r) * Cc + j0 + c4);
  tile[r][c4 + 0] = v[0]; tile[r][c4 + 1] = v[1];
  tile[r][c4 + 2] = v[2]; tile[r][c4 + 3] = v[3];
  __syncthreads();
  us4v o = { f2bf(tile[c4 + 0][r]), f2bf(tile[c4 + 1][r]),
             f2bf(tile[c4 + 2][r]), f2bf(tile[c4 + 3][r]) };
  *(us4v*)(dst + (int64_t)(j0 + r) * 768 + k0 + c4) = o;
}

// ---------------- GEMM: C = A[M,K] * Bt[N,K]^T + bias ----------------
template<int MODE>
__global__ __launch_bounds__(256) void k_gemm(
    const unsigned short* __restrict__ A, const unsigned short* __restrict__ Bt,
    const float* __restrict__ bias, int M, int N, int K,
    unsigned short* __restrict__ qb, unsigned short* __restrict__ kb,
    unsigned short* __restrict__ vtb, float* __restrict__ outp)
{
  __shared__ __align__(16) unsigned short At [128 * 32];
  __shared__ __align__(16) unsigned short Btl[128 * 32];
  const int tid = threadIdx.x, lane = tid & 63, wid = tid >> 6;
  const int mbase = blockIdx.y * 128, nbase = blockIdx.x * 128;
  const int wr = wid >> 1, wc = wid & 1;
  const int g = lane >> 4, l15 = lane & 15;
  const int l2 = lane >> 2, l3 = lane & 3;
  f4v acc[4][4] = {};

  int srow0 = wid * 16 + l2;
  int srow1 = 64 + wid * 16 + l2;
  int sg0 = l3 ^ ((srow0 >> 1) & 3);
  int sg1 = l3 ^ ((srow1 >> 1) & 3);
  int arow0 = mbase + srow0; if (arow0 >= M) arow0 = 0;
  int arow1 = mbase + srow1; if (arow1 >= M) arow1 = 0;
  const unsigned short* a0 = A  + (int64_t)arow0 * K + sg0 * 8;
  const unsigned short* a1 = A  + (int64_t)arow1 * K + sg1 * 8;
  const unsigned short* b0 = Bt + (int64_t)(nbase + srow0) * K + sg0 * 8;
  const unsigned short* b1 = Bt + (int64_t)(nbase + srow1) * K + sg1 * 8;
  unsigned short* lA0 = At  + wid * 16 * 32;
  unsigned short* lA1 = At  + (64 + wid * 16) * 32;
  unsigned short* lB0 = Btl + wid * 16 * 32;
  unsigned short* lB1 = Btl + (64 + wid * 16) * 32;

  for (int ks = 0; ks < K; ks += 32){
    load_lds16(a0 + ks, lA0);
    load_lds16(a1 + ks, lA1);
    load_lds16(b0 + ks, lB0);
    load_lds16(b1 + ks, lB1);
    __syncthreads();
    s8v af[4], bf[4];
    #pragma unroll
    for (int mc = 0; mc < 4; mc++){
      int row = wr * 64 + mc * 16 + l15;
      int o = (row * 64 + g * 16) ^ (((row >> 1) & 3) << 4);
      af[mc] = *(const s8v*)((const char*)At + o);
    }
    #pragma unroll
    for (int nc = 0; nc < 4; nc++){
      int row = wc * 64 + nc * 16 + l15;
      int o = (row * 64 + g * 16) ^ (((row >> 1) & 3) << 4);
      bf[nc] = *(const s8v*)((const char*)Btl + o);
    }
    #pragma unroll
    for (int mc = 0; mc < 4; mc++)
      #pragma unroll
      for (int nc = 0; nc < 4; nc++)
        acc[mc][nc] = mfma32(af[mc], bf[nc], acc[mc][nc]);
    __syncthreads();
  }

  if (MODE == 0){
    const int which = nbase / 768;
    const int head  = ((nbase % 768) >> 6) + wc;
    #pragma unroll
    for (int nc = 0; nc < 4; nc++){
      int j = nbase + wc * 64 + nc * 16 + l15;
      float bv = bias[j];
      int d = nc * 16 + l15;
      #pragma unroll
      for (int mc = 0; mc < 4; mc++){
        int m0 = mbase + wr * 64 + mc * 16 + g * 4;
        if (m0 >= M) continue;
        int b = m0 / 1032, n = m0 % 1032;
        int bh = b * 12 + head;
        if (which == 2){
          us4v pk = { f2bf(acc[mc][nc][0] + bv), f2bf(acc[mc][nc][1] + bv),
                      f2bf(acc[mc][nc][2] + bv), f2bf(acc[mc][nc][3] + bv) };
          *(us4v*)(vtb + ((int64_t)bh * 64 + d) * 1032 + n) = pk;
        } else {
          unsigned short* dst = (which == 0 ? qb : kb) + ((int64_t)bh * 1032 + n) * 64 + d;
          #pragma unroll
          for (int r = 0; r < 4; r++) dst[(int64_t)r * 64] = f2bf(acc[mc][nc][r] + bv);
        }
      }
    }
  } else {
    #pragma unroll
    for (int nc = 0; nc < 4; nc++){
      int j = nbase + wc * 64 + nc * 16 + l15;
      float bv = bias[j];
      #pragma unroll
      for (int mc = 0; mc < 4; mc++){
        int m0 = mbase + wr * 64 + mc * 16 + g * 4;
        if (m0 >= M) continue;
        int b = m0 / 1032, n0 = m0 % 1032;
        #pragma unroll
        for (int r = 0; r < 4; r++){
          int n = n0 + r;
          float v = acc[mc][nc][r] + bv;
          int64_t dst = (n < 8) ? (6291456LL + ((int64_t)(b * 8 + n)) * 768 + j)
                                : (((int64_t)(b * 1024 + (n - 8))) * 768 + j);
          outp[dst] = v;
        }
      }
    }
  }
}

// ---------------- rel_h: [bh][kh][qp] = (q . Rh) * log2e ----------------
__global__ __launch_bounds__(64) void k_rel_h(const unsigned short* __restrict__ qbuf,
    const float* __restrict__ rph, float* __restrict__ relh)
{
  const int lane = threadIdx.x;
  const int bh = blockIdx.x >> 5;
  const int qh = blockIdx.x & 31;
  const int g = lane >> 4, l15 = lane & 15;
  s8v qf[2][2];
  #pragma unroll
  for (int qc = 0; qc < 2; qc++){
    int n = qh * 32 + qc * 16 + l15 + 8;
    #pragma unroll
    for (int ch = 0; ch < 2; ch++)
      qf[qc][ch] = *(const s8v*)(qbuf + ((int64_t)bh * 1032 + n) * 64 + ch * 32 + g * 8);
  }
  s8v rf[2][2];
  #pragma unroll
  for (int kc = 0; kc < 2; kc++){
    int kh = kc * 16 + l15;
    #pragma unroll
    for (int ch = 0; ch < 2; ch++){
      const float* rp = rph + (int64_t)(qh - kh + 31) * 64 + ch * 32 + g * 8;
      f32x4v v0 = *(const f32x4v*)rp;
      f32x4v v1 = *(const f32x4v*)(rp + 4);
      s8v t = { (short)f2bf(v0[0]), (short)f2bf(v0[1]), (short)f2bf(v0[2]), (short)f2bf(v0[3]),
                (short)f2bf(v1[0]), (short)f2bf(v1[1]), (short)f2bf(v1[2]), (short)f2bf(v1[3]) };
      rf[kc][ch] = t;
    }
  }
  #pragma unroll
  for (int kc = 0; kc < 2; kc++)
    #pragma unroll
    for (int qc = 0; qc < 2; qc++){
      f4v d = {0.f, 0.f, 0.f, 0.f};
      d = mfma32(rf[kc][0], qf[qc][0], d);
      d = mfma32(rf[kc][1], qf[qc][1], d);
      #pragma unroll
      for (int r = 0; r < 4; r++)
        relh[((int64_t)bh * 32 + kc * 16 + g * 4 + r) * 1024 + qh * 32 + qc * 16 + l15] = d[r] * L2E;
    }
}

// ---------------- rel_w: [bh][qp][kw] = (q . Rw) * log2e ----------------
__global__ __launch_bounds__(64) void k_rel_w(const unsigned short* __restrict__ qbuf,
    const float* __restrict__ rpw, float* __restrict__ relw)
{
  const int lane = threadIdx.x;
  const int bh = blockIdx.x >> 5;
  const int qw = blockIdx.x & 31;
  const int g = lane >> 4, l15 = lane & 15;
  s8v qf[2][2];
  #pragma unroll
  for (int qc = 0; qc < 2; qc++){
    int qp = qw + 32 * (qc * 16 + l15);
    int n = qp + 8;
    #pragma unroll
    for (int ch = 0; ch < 2; ch++)
      qf[qc][ch] = *(const s8v*)(qbuf + ((int64_t)bh * 1032 + n) * 64 + ch * 32 + g * 8);
  }
  s8v wf[2][2];
  #pragma unroll
  for (int kc = 0; kc < 2; kc++){
    int kw = kc * 16 + l15;
    #pragma unroll
    for (int ch = 0; ch < 2; ch++){
      const float* rp = rpw + (int64_t)(qw - kw + 31) * 64 + ch * 32 + g * 8;
      f32x4v v0 = *(const f32x4v*)rp;
      f32x4v v1 = *(const f32x4v*)(rp + 4);
      s8v t = { (short)f2bf(v0[0]), (short)f2bf(v0[1]), (short)f2bf(v0[2]), (short)f2bf(v0[3]),
                (short)f2bf(v1[0]), (short)f2bf(v1[1]), (short)f2bf(v1[2]), (short)f2bf(v1[3]) };
      wf[kc][ch] = t;
    }
  }
  #pragma unroll
  for (int qc = 0; qc < 2; qc++)
    #pragma unroll
    for (int kc = 0; kc < 2; kc++){
      f4v d = {0.f, 0.f, 0.f, 0.f};
      d = mfma32(qf[qc][0], wf[kc][0], d);
      d = mfma32(qf[qc][1], wf[kc][1], d);
      #pragma unroll
      for (int r = 0; r < 4; r++){
        int qp = qw + 32 * (qc * 16 + g * 4 + r);
        relw[((int64_t)bh * 1024 + qp) * 32 + kc * 16 + l15] = d[r] * L2E;
      }
    }
}

// ---------------- flash attention, 4-way K-split, running max (r2 core) ----------------
// Grid: 96 bh x 33 q-tiles; 4 waves = 4 K-chunks {0..8, 9..16, 17..24, 25..32}.
// Waves 1..3 publish (m, l-partial, O-partial) to LDS; wave 0 merges + stores.
// K fragments register-prefetched one tile ahead; l accumulated per-lane
// (alpha is row-uniform) and g-reduced once at the end.
__global__ __launch_bounds__(256, 3) void k_attn(
    const unsigned short* __restrict__ qb, const unsigned short* __restrict__ kb,
    const unsigned short* __restrict__ vtb, const float* __restrict__ relh,
    const float* __restrict__ relw, unsigned short* __restrict__ ao)
{
  const int lane = threadIdx.x & 63, wid = threadIdx.x >> 6;
  const int bh = blockIdx.x / 33;
  const int qt = blockIdx.x % 33;
  const int qbase = qt * 32;
  const int g = lane >> 4, l15 = lane & 15;
  const int b = bh / 12, head = bh % 12;
  const float C1 = 0.125f * L2E;

  __shared__ __align__(16) float ofs[3][4][2][64][4];  // 24 KB: waves 1..3 O-partials
  __shared__ float mls[3][2][64][2];                   // 3 KB: m (row-uniform), l per-lane

  const int kt_lo = (wid == 0) ? 0 : 1 + wid * 8;      // {0, 9, 17, 25}
  const int kt_hi = 1 + (wid + 1) * 8;                 // {9, 17, 25, 33}

  f4v of[4][2] = {};
  float mrun[2] = {-3.0e38f, -3.0e38f};
  float lrun[2] = {0.f, 0.f};
  int qn_[2], qp_[2];

  s8v qf[2][2];
  float rw[2][2][4];
  #pragma unroll
  for (int qc = 0; qc < 2; qc++){
    int qn = qbase + qc * 16 + l15;
    qn_[qc] = qn;
    int qcl = qn < 1032 ? qn : 1031;
    #pragma unroll
    for (int ch = 0; ch < 2; ch++)
      qf[qc][ch] = *(const s8v*)(qb + ((int64_t)bh * 1032 + qcl) * 64 + ch * 32 + g * 8);
    int qp = qn - 8; if (qp < 0) qp = 0; if (qp > 1023) qp = 1023;
    qp_[qc] = qp;
  }
  #pragma unroll
  for (int qc = 0; qc < 2; qc++)
    #pragma unroll
    for (int kc = 0; kc < 2; kc++)
      #pragma unroll
      for (int r = 0; r < 4; r++){
        int kw = (kc * 16 + g * 4 + r + 24) & 31;
        rw[qc][kc][r] = relw[((int64_t)bh * 1024 + qp_[qc]) * 32 + kw];
      }

  const unsigned short* vbase = vtb + (int64_t)bh * 64 * 1032;
  const unsigned short* kbase = kb + (int64_t)bh * 1032 * 64;
  const float* rhbase = relh + (int64_t)bh * 32 * 1024;

  // prefetch K fragments for first tile of this wave's chunk
  s8v kfc[2][2];
  #pragma unroll
  for (int kc = 0; kc < 2; kc++){
    int key = kt_lo * 32 + kc * 16 + l15; if (key > 1031) key = 1031;
    #pragma unroll
    for (int ch = 0; ch < 2; ch++)
      kfc[kc][ch] = *(const s8v*)(kbase + (int64_t)key * 64 + ch * 32 + g * 8);
  }

  for (int kt = kt_lo; kt < kt_hi; kt++){
    // prefetch next tile's K
    int ktn = (kt + 1 < kt_hi) ? kt + 1 : kt;
    s8v kfn[2][2];
    #pragma unroll
    for (int kc = 0; kc < 2; kc++){
      int key = ktn * 32 + kc * 16 + l15; if (key > 1031) key = 1031;
      #pragma unroll
      for (int ch = 0; ch < 2; ch++)
        kfn[kc][ch] = *(const s8v*)(kbase + (int64_t)key * 64 + ch * 32 + g * 8);
    }
    // V fragments (clamped so no row-overrun; clamped slots have zero weight)
    s4v vf[4][2];
    #pragma unroll
    for (int kc = 0; kc < 2; kc++){
      int kvo = kt * 32 + kc * 16 + g * 4; if (kvo > 1028) kvo = 1028;
      #pragma unroll
      for (int dc = 0; dc < 4; dc++)
        vf[dc][kc] = *(const s4v*)(vbase + (int64_t)(dc * 16 + l15) * 1032 + kvo);
    }
    // rel_h values
    int khA = kt - 1; if (khA < 0) khA = 0;
    int khB = kt; if (khB > 31) khB = 31;
    float rhA[2], rhB[2];
    #pragma unroll
    for (int qc = 0; qc < 2; qc++){
      rhA[qc] = rhbase[(int64_t)khA * 1024 + qp_[qc]];
      rhB[qc] = rhbase[(int64_t)khB * 1024 + qp_[qc]];
    }
    // QK^T (swapped: lane col = query)
    f4v sv[2][2];
    #pragma unroll
    for (int qc = 0; qc < 2; qc++)
      #pragma unroll
      for (int kc = 0; kc < 2; kc++){
        f4v s = {0.f, 0.f, 0.f, 0.f};
        s = mfma32(kfc[kc][0], qf[qc][0], s);
        s = mfma32(kfc[kc][1], qf[qc][1], s);
        sv[qc][kc] = s;
      }
    const bool anyprompt = (kt == 0);
    const bool anymask = (kt == 32);
    s4v bp[2][2];
    #pragma unroll
    for (int qc = 0; qc < 2; qc++){
      const bool qpr = qn_[qc] < 8;
      float pc[2][4];
      #pragma unroll
      for (int kc = 0; kc < 2; kc++)
        #pragma unroll
        for (int r = 0; r < 4; r++){
          int off = kc * 16 + g * 4 + r;
          float bias = qpr ? 0.f : ((off >= 8 ? rhB[qc] : rhA[qc]) + rw[qc][kc][r]);
          if (anyprompt && off < 8 && !qpr) bias = -144.269504f;
          float L = fmaf(sv[qc][kc][r], C1, bias);
          if (anymask && off >= 8) L = -3.0e38f;
          pc[kc][r] = L;
        }
      float tm = fmaxf(fmaxf(fmaxf(pc[0][0], pc[0][1]), fmaxf(pc[0][2], pc[0][3])),
                       fmaxf(fmaxf(pc[1][0], pc[1][1]), fmaxf(pc[1][2], pc[1][3])));
      tm = fmaxf(tm, __shfl_xor(tm, 16));
      tm = fmaxf(tm, __shfl_xor(tm, 32));
      if (!__all(tm <= mrun[qc])){
        float mnew = fmaxf(mrun[qc], tm);
        float alpha = exp2g(mrun[qc] - mnew);
        mrun[qc] = mnew;
        lrun[qc] *= alpha;
        #pragma unroll
        for (int dc = 0; dc < 4; dc++)
          of[dc][qc] = of[dc][qc] * alpha;
      }
      float m = mrun[qc];
      float p[8];
      #pragma unroll
      for (int kc = 0; kc < 2; kc++)
        #pragma unroll
        for (int r = 0; r < 4; r++)
          p[kc * 4 + r] = exp2g(pc[kc][r] - m);
      lrun[qc] += ((p[0]+p[1])+(p[2]+p[3])) + ((p[4]+p[5])+(p[6]+p[7]));  // per-lane partial
      bp[qc][0] = pack4(p[0], p[1], p[2], p[3]);
      bp[qc][1] = pack4(p[4], p[5], p[6], p[7]);
    }
    // PV
    #pragma unroll
    for (int dc = 0; dc < 4; dc++)
      #pragma unroll
      for (int kc = 0; kc < 2; kc++)
        #pragma unroll
        for (int qc = 0; qc < 2; qc++)
          of[dc][qc] = mfma16(vf[dc][kc], bp[qc][kc], of[dc][qc]);
    // roll prefetch
    #pragma unroll
    for (int kc = 0; kc < 2; kc++)
      #pragma unroll
      for (int ch = 0; ch < 2; ch++)
        kfc[kc][ch] = kfn[kc][ch];
  }

  // publish partials (waves 1..3)
  if (wid >= 1){
    #pragma unroll
    for (int dc = 0; dc < 4; dc++)
      #pragma unroll
      for (int qc = 0; qc < 2; qc++)
        *(f4v*)&ofs[wid - 1][dc][qc][lane][0] = of[dc][qc];
    #pragma unroll
    for (int qc = 0; qc < 2; qc++){
      mls[wid - 1][qc][lane][0] = mrun[qc];
      mls[wid - 1][qc][lane][1] = lrun[qc];
    }
  }
  __syncthreads();
  // merge + store (wave 0)
  if (wid == 0){
    #pragma unroll
    for (int qc = 0; qc < 2; qc++){
      int qn = qn_[qc];
      if (qn >= 1032) continue;
      float M = mrun[qc];
      #pragma unroll
      for (int w = 0; w < 3; w++) M = fmaxf(M, mls[w][qc][lane][0]);
      float a0 = exp2g(mrun[qc] - M);
      float lt = lrun[qc] * a0;
      f4v ot[4];
      #pragma unroll
      for (int dc = 0; dc < 4; dc++) ot[dc] = of[dc][qc] * a0;
      #pragma unroll
      for (int w = 0; w < 3; w++){
        float aw = exp2g(mls[w][qc][lane][0] - M);
        lt += mls[w][qc][lane][1] * aw;
        #pragma unroll
        for (int dc = 0; dc < 4; dc++)
          ot[dc] += (*(const f4v*)&ofs[w][dc][qc][lane][0]) * aw;
      }
      lt += __shfl_xor(lt, 16);
      lt += __shfl_xor(lt, 32);
      float inv = 1.0f / lt;
      unsigned short* dst = ao + ((int64_t)(b * 1032 + qn)) * 768 + head * 64;
      #pragma unroll
      for (int dc = 0; dc < 4; dc++){
        us4v pk = { f2bf(ot[dc][0] * inv), f2bf(ot[dc][1] * inv),
                    f2bf(ot[dc][2] * inv), f2bf(ot[dc][3] * inv) };
        *(us4v*)(dst + dc * 16 + g * 4) = pk;
      }
    }
  }
}

extern "C" void kernel_launch(void* const* d_in, const int* in_sizes, int n_in,
                              void* d_out, int out_size, void* d_ws, size_t ws_size,
                              hipStream_t stream)
{
  const float* x   = (const float*)d_in[0];
  const float* vp  = (const float*)d_in[1];
  const float* qw  = (const float*)d_in[2];
  const float* qbb = (const float*)d_in[3];
  const float* pw  = (const float*)d_in[4];
  const float* pb  = (const float*)d_in[5];
  const float* rph = (const float*)d_in[6];
  const float* rpw = (const float*)d_in[7];
  float* out = (float*)d_out;

  char* ws = (char*)d_ws;
  size_t off = 0;
  auto alloc = [&](size_t bytes) -> void* {
    void* p = ws + off;
    off = (off + bytes + 255) & ~(size_t)255;
    return p;
  };
  unsigned short* xs   = (unsigned short*)alloc((size_t)8256 * 768 * 2);
  unsigned short* Wt   = (unsigned short*)alloc((size_t)2304 * 768 * 2);
  unsigned short* Pt   = (unsigned short*)alloc((size_t)768 * 768 * 2);
  unsigned short* qbuf = (unsigned short*)alloc((size_t)96 * 1032 * 64 * 2);
  unsigned short* kbuf = (unsigned short*)alloc((size_t)96 * 1032 * 64 * 2);
  unsigned short* vtb  = (unsigned short*)alloc((size_t)96 * 64 * 1032 * 2 + 256);
  float* relh = (float*)alloc((size_t)96 * 32 * 1024 * 4);
  float* relw = (float*)alloc((size_t)96 * 1024 * 32 * 4);
  unsigned short* ao = xs;  // xs dead after QKV GEMM; reuse for attention output

  k_prep_xs<<<6192, 256, 0, stream>>>(x, vp, xs);
  k_prep_w<<<2304, 256, 0, stream>>>(qw, pw, Wt, Pt);
  k_gemm<0><<<dim3(18, 65), 256, 0, stream>>>(xs, Wt, qbb, 8256, 2304, 768,
                                              qbuf, kbuf, vtb, nullptr);
  k_rel_h<<<3072, 64, 0, stream>>>(qbuf, rph, relh);
  k_rel_w<<<3072, 64, 0, stream>>>(qbuf, rpw, relw);
  k_attn<<<3168, 256, 0, stream>>>(qbuf, kbuf, vtb, relh, relw, ao);
  k_gemm<1><<<dim3(6, 65), 256, 0, stream>>>(ao, Pt, pb, 8256, 768, 768,
                                             nullptr, nullptr, nullptr, out);
}

// Round 5
// 223.988 us; speedup vs baseline: 1.1368x; 1.0403x over previous
//
#include <hip/hip_runtime.h>
#include <stdint.h>

typedef __attribute__((ext_vector_type(8))) short s8v;
typedef __attribute__((ext_vector_type(4))) short s4v;
typedef __attribute__((ext_vector_type(4))) float f4v;
typedef __attribute__((ext_vector_type(4))) unsigned short us4v;
typedef __attribute__((ext_vector_type(4))) float f32x4v;

#define DEV static __device__ __forceinline__

#define L2E 1.44269504f

DEV unsigned short f2bf(float f){
  uint32_t x = __builtin_bit_cast(uint32_t, f);
  uint32_t r = x + 0x7fffu + ((x >> 16) & 1u);
  return (unsigned short)(r >> 16);
}

DEV float exp2g(float x){
#if __has_builtin(__builtin_amdgcn_exp2f)
  return __builtin_amdgcn_exp2f(x);
#else
  return exp2f(x);
#endif
}

// pack 4 f32 -> 4 bf16 (two v_cvt_pk_bf16_f32, RNE — same as f2bf)
DEV s4v pack4(float a, float b, float c, float d){
  uint32_t r0, r1;
  asm("v_cvt_pk_bf16_f32 %0, %1, %2" : "=v"(r0) : "v"(a), "v"(b));
  asm("v_cvt_pk_bf16_f32 %0, %1, %2" : "=v"(r1) : "v"(c), "v"(d));
  union { uint32_t u[2]; s4v s; } u; u.u[0] = r0; u.u[1] = r1; return u.s;
}

DEV f4v mfma32(s8v a, s8v b, f4v c){
  return __builtin_amdgcn_mfma_f32_16x16x32_bf16(a, b, c, 0, 0, 0);
}
DEV f4v mfma16(s4v a, s4v b, f4v c){
  return __builtin_amdgcn_mfma_f32_16x16x16bf16_1k(a, b, c, 0, 0, 0);
}

DEV void load_lds16(const void* g, void* l){
  __builtin_amdgcn_global_load_lds((const __attribute__((address_space(1))) uint32_t*)g,
                                   (__attribute__((address_space(3))) uint32_t*)l, 16, 0, 0);
}

// ---------------- prep: xs = concat(vp, x) -> bf16 ----------------
__global__ void k_prep_xs(const float* __restrict__ x, const float* __restrict__ vp,
                          unsigned short* __restrict__ xs){
  int64_t e = ((int64_t)blockIdx.x * 256 + threadIdx.x) * 4;
  int m = (int)(e / 768); int c = (int)(e % 768);
  int b = m / 1032, n = m % 1032;
  const float* src = (n < 8) ? (vp + ((int64_t)(b * 8 + n)) * 768 + c)
                             : (x  + ((int64_t)(b * 1024 + (n - 8))) * 768 + c);
  f32x4v v = *(const f32x4v*)src;
  us4v o = { f2bf(v[0]), f2bf(v[1]), f2bf(v[2]), f2bf(v[3]) };
  *(us4v*)(xs + e) = o;
}

// ---------------- prep: W transposes -> bf16 (LDS tile transpose) ----------------
// qw [768][2304] -> Wt [2304][768]; pw [768][768] -> Pt [768][768]
__global__ __launch_bounds__(256) void k_prep_w(const float* __restrict__ qw,
    const float* __restrict__ pw, unsigned short* __restrict__ Wt,
    unsigned short* __restrict__ Pt){
  __shared__ float tile[32][33];
  const int bid = blockIdx.x;
  const float* src; unsigned short* dst; int Cc, j0, k0;
  if (bid < 1728){
    int jt = bid % 72, kt = bid / 72;
    src = qw; dst = Wt; Cc = 2304; k0 = kt * 32; j0 = jt * 32;
  } else {
    int t2 = bid - 1728;
    int jt = t2 % 24, kt = t2 / 24;
    src = pw; dst = Pt; Cc = 768; k0 = kt * 32; j0 = jt * 32;
  }
  const int t = threadIdx.x;
  const int r = t >> 3, c4 = (t & 7) * 4;
  f32x4v v = *(const f32x4v*)(src + (int64_t)(k0 + r) * Cc + j0 + c4);
  tile[r][c4 + 0] = v[0]; tile[r][c4 + 1] = v[1];
  tile[r][c4 + 2] = v[2]; tile[r][c4 + 3] = v[3];
  __syncthreads();
  us4v o = { f2bf(tile[c4 + 0][r]), f2bf(tile[c4 + 1][r]),
             f2bf(tile[c4 + 2][r]), f2bf(tile[c4 + 3][r]) };
  *(us4v*)(dst + (int64_t)(j0 + r) * 768 + k0 + c4) = o;
}

// ---------------- GEMM: C = A[M,K] * Bt[N,K]^T + bias ----------------
template<int MODE>
__global__ __launch_bounds__(256) void k_gemm(
    const unsigned short* __restrict__ A, const unsigned short* __restrict__ Bt,
    const float* __restrict__ bias, int M, int N, int K,
    unsigned short* __restrict__ qb, unsigned short* __restrict__ kb,
    unsigned short* __restrict__ vtb, float* __restrict__ outp)
{
  __shared__ __align__(16) unsigned short At [128 * 32];
  __shared__ __align__(16) unsigned short Btl[128 * 32];
  const int tid = threadIdx.x, lane = tid & 63, wid = tid >> 6;
  const int mbase = blockIdx.y * 128, nbase = blockIdx.x * 128;
  const int wr = wid >> 1, wc = wid & 1;
  const int g = lane >> 4, l15 = lane & 15;
  const int l2 = lane >> 2, l3 = lane & 3;
  f4v acc[4][4] = {};

  int srow0 = wid * 16 + l2;
  int srow1 = 64 + wid * 16 + l2;
  int sg0 = l3 ^ ((srow0 >> 1) & 3);
  int sg1 = l3 ^ ((srow1 >> 1) & 3);
  int arow0 = mbase + srow0; if (arow0 >= M) arow0 = 0;
  int arow1 = mbase + srow1; if (arow1 >= M) arow1 = 0;
  const unsigned short* a0 = A  + (int64_t)arow0 * K + sg0 * 8;
  const unsigned short* a1 = A  + (int64_t)arow1 * K + sg1 * 8;
  const unsigned short* b0 = Bt + (int64_t)(nbase + srow0) * K + sg0 * 8;
  const unsigned short* b1 = Bt + (int64_t)(nbase + srow1) * K + sg1 * 8;
  unsigned short* lA0 = At  + wid * 16 * 32;
  unsigned short* lA1 = At  + (64 + wid * 16) * 32;
  unsigned short* lB0 = Btl + wid * 16 * 32;
  unsigned short* lB1 = Btl + (64 + wid * 16) * 32;

  for (int ks = 0; ks < K; ks += 32){
    load_lds16(a0 + ks, lA0);
    load_lds16(a1 + ks, lA1);
    load_lds16(b0 + ks, lB0);
    load_lds16(b1 + ks, lB1);
    __syncthreads();
    s8v af[4], bf[4];
    #pragma unroll
    for (int mc = 0; mc < 4; mc++){
      int row = wr * 64 + mc * 16 + l15;
      int o = (row * 64 + g * 16) ^ (((row >> 1) & 3) << 4);
      af[mc] = *(const s8v*)((const char*)At + o);
    }
    #pragma unroll
    for (int nc = 0; nc < 4; nc++){
      int row = wc * 64 + nc * 16 + l15;
      int o = (row * 64 + g * 16) ^ (((row >> 1) & 3) << 4);
      bf[nc] = *(const s8v*)((const char*)Btl + o);
    }
    #pragma unroll
    for (int mc = 0; mc < 4; mc++)
      #pragma unroll
      for (int nc = 0; nc < 4; nc++)
        acc[mc][nc] = mfma32(af[mc], bf[nc], acc[mc][nc]);
    __syncthreads();
  }

  if (MODE == 0){
    const int which = nbase / 768;
    const int head  = ((nbase % 768) >> 6) + wc;
    #pragma unroll
    for (int nc = 0; nc < 4; nc++){
      int j = nbase + wc * 64 + nc * 16 + l15;
      float bv = bias[j];
      int d = nc * 16 + l15;
      #pragma unroll
      for (int mc = 0; mc < 4; mc++){
        int m0 = mbase + wr * 64 + mc * 16 + g * 4;
        if (m0 >= M) continue;
        int b = m0 / 1032, n = m0 % 1032;
        int bh = b * 12 + head;
        if (which == 2){
          us4v pk = { f2bf(acc[mc][nc][0] + bv), f2bf(acc[mc][nc][1] + bv),
                      f2bf(acc[mc][nc][2] + bv), f2bf(acc[mc][nc][3] + bv) };
          *(us4v*)(vtb + ((int64_t)bh * 64 + d) * 1032 + n) = pk;
        } else {
          unsigned short* dst = (which == 0 ? qb : kb) + ((int64_t)bh * 1032 + n) * 64 + d;
          #pragma unroll
          for (int r = 0; r < 4; r++) dst[(int64_t)r * 64] = f2bf(acc[mc][nc][r] + bv);
        }
      }
    }
  } else {
    #pragma unroll
    for (int nc = 0; nc < 4; nc++){
      int j = nbase + wc * 64 + nc * 16 + l15;
      float bv = bias[j];
      #pragma unroll
      for (int mc = 0; mc < 4; mc++){
        int m0 = mbase + wr * 64 + mc * 16 + g * 4;
        if (m0 >= M) continue;
        int b = m0 / 1032, n0 = m0 % 1032;
        #pragma unroll
        for (int r = 0; r < 4; r++){
          int n = n0 + r;
          float v = acc[mc][nc][r] + bv;
          int64_t dst = (n < 8) ? (6291456LL + ((int64_t)(b * 8 + n)) * 768 + j)
                                : (((int64_t)(b * 1024 + (n - 8))) * 768 + j);
          outp[dst] = v;
        }
      }
    }
  }
}

// ---------------- rel_h: [bh][kh][qp] = (q . Rh) * log2e ----------------
__global__ __launch_bounds__(64) void k_rel_h(const unsigned short* __restrict__ qbuf,
    const float* __restrict__ rph, float* __restrict__ relh)
{
  const int lane = threadIdx.x;
  const int bh = blockIdx.x >> 5;
  const int qh = blockIdx.x & 31;
  const int g = lane >> 4, l15 = lane & 15;
  s8v qf[2][2];
  #pragma unroll
  for (int qc = 0; qc < 2; qc++){
    int n = qh * 32 + qc * 16 + l15 + 8;
    #pragma unroll
    for (int ch = 0; ch < 2; ch++)
      qf[qc][ch] = *(const s8v*)(qbuf + ((int64_t)bh * 1032 + n) * 64 + ch * 32 + g * 8);
  }
  s8v rf[2][2];
  #pragma unroll
  for (int kc = 0; kc < 2; kc++){
    int kh = kc * 16 + l15;
    #pragma unroll
    for (int ch = 0; ch < 2; ch++){
      const float* rp = rph + (int64_t)(qh - kh + 31) * 64 + ch * 32 + g * 8;
      f32x4v v0 = *(const f32x4v*)rp;
      f32x4v v1 = *(const f32x4v*)(rp + 4);
      s8v t = { (short)f2bf(v0[0]), (short)f2bf(v0[1]), (short)f2bf(v0[2]), (short)f2bf(v0[3]),
                (short)f2bf(v1[0]), (short)f2bf(v1[1]), (short)f2bf(v1[2]), (short)f2bf(v1[3]) };
      rf[kc][ch] = t;
    }
  }
  #pragma unroll
  for (int kc = 0; kc < 2; kc++)
    #pragma unroll
    for (int qc = 0; qc < 2; qc++){
      f4v d = {0.f, 0.f, 0.f, 0.f};
      d = mfma32(rf[kc][0], qf[qc][0], d);
      d = mfma32(rf[kc][1], qf[qc][1], d);
      #pragma unroll
      for (int r = 0; r < 4; r++)
        relh[((int64_t)bh * 32 + kc * 16 + g * 4 + r) * 1024 + qh * 32 + qc * 16 + l15] = d[r] * L2E;
    }
}

// ---------------- rel_w: [bh][qp][kw] = (q . Rw) * log2e ----------------
__global__ __launch_bounds__(64) void k_rel_w(const unsigned short* __restrict__ qbuf,
    const float* __restrict__ rpw, float* __restrict__ relw)
{
  const int lane = threadIdx.x;
  const int bh = blockIdx.x >> 5;
  const int qw = blockIdx.x & 31;
  const int g = lane >> 4, l15 = lane & 15;
  s8v qf[2][2];
  #pragma unroll
  for (int qc = 0; qc < 2; qc++){
    int qp = qw + 32 * (qc * 16 + l15);
    int n = qp + 8;
    #pragma unroll
    for (int ch = 0; ch < 2; ch++)
      qf[qc][ch] = *(const s8v*)(qbuf + ((int64_t)bh * 1032 + n) * 64 + ch * 32 + g * 8);
  }
  s8v wf[2][2];
  #pragma unroll
  for (int kc = 0; kc < 2; kc++){
    int kw = kc * 16 + l15;
    #pragma unroll
    for (int ch = 0; ch < 2; ch++){
      const float* rp = rpw + (int64_t)(qw - kw + 31) * 64 + ch * 32 + g * 8;
      f32x4v v0 = *(const f32x4v*)rp;
      f32x4v v1 = *(const f32x4v*)(rp + 4);
      s8v t = { (short)f2bf(v0[0]), (short)f2bf(v0[1]), (short)f2bf(v0[2]), (short)f2bf(v0[3]),
                (short)f2bf(v1[0]), (short)f2bf(v1[1]), (short)f2bf(v1[2]), (short)f2bf(v1[3]) };
      wf[kc][ch] = t;
    }
  }
  #pragma unroll
  for (int qc = 0; qc < 2; qc++)
    #pragma unroll
    for (int kc = 0; kc < 2; kc++){
      f4v d = {0.f, 0.f, 0.f, 0.f};
      d = mfma32(qf[qc][0], wf[kc][0], d);
      d = mfma32(qf[qc][1], wf[kc][1], d);
      #pragma unroll
      for (int r = 0; r < 4; r++){
        int qp = qw + 32 * (qc * 16 + g * 4 + r);
        relw[((int64_t)bh * 1024 + qp) * 32 + kc * 16 + l15] = d[r] * L2E;
      }
    }
}

// ---------------- flash attention, 4-way K-split, running max ----------------
// Identical to round-4 core; ONE change: XCD-bijective blockIdx swizzle so
// each XCD owns 12 consecutive bh (all 33 q-tiles of a bh on one XCD's L2).
// 3168 blocks % 8 XCDs == 0 -> w = (bid%8)*396 + bid/8 is bijective.
__global__ __launch_bounds__(256, 3) void k_attn(
    const unsigned short* __restrict__ qb, const unsigned short* __restrict__ kb,
    const unsigned short* __restrict__ vtb, const float* __restrict__ relh,
    const float* __restrict__ relw, unsigned short* __restrict__ ao)
{
  const int lane = threadIdx.x & 63, wid = threadIdx.x >> 6;
  const int wq = (blockIdx.x & 7) * 396 + (blockIdx.x >> 3);  // XCD swizzle (T1)
  const int bh = wq / 33;
  const int qt = wq % 33;
  const int qbase = qt * 32;
  const int g = lane >> 4, l15 = lane & 15;
  const int b = bh / 12, head = bh % 12;
  const float C1 = 0.125f * L2E;

  __shared__ __align__(16) float ofs[3][4][2][64][4];  // 24 KB: waves 1..3 O-partials
  __shared__ float mls[3][2][64][2];                   // 3 KB: m (row-uniform), l per-lane

  const int kt_lo = (wid == 0) ? 0 : 1 + wid * 8;      // {0, 9, 17, 25}
  const int kt_hi = 1 + (wid + 1) * 8;                 // {9, 17, 25, 33}

  f4v of[4][2] = {};
  float mrun[2] = {-3.0e38f, -3.0e38f};
  float lrun[2] = {0.f, 0.f};
  int qn_[2], qp_[2];

  s8v qf[2][2];
  float rw[2][2][4];
  #pragma unroll
  for (int qc = 0; qc < 2; qc++){
    int qn = qbase + qc * 16 + l15;
    qn_[qc] = qn;
    int qcl = qn < 1032 ? qn : 1031;
    #pragma unroll
    for (int ch = 0; ch < 2; ch++)
      qf[qc][ch] = *(const s8v*)(qb + ((int64_t)bh * 1032 + qcl) * 64 + ch * 32 + g * 8);
    int qp = qn - 8; if (qp < 0) qp = 0; if (qp > 1023) qp = 1023;
    qp_[qc] = qp;
  }
  #pragma unroll
  for (int qc = 0; qc < 2; qc++)
    #pragma unroll
    for (int kc = 0; kc < 2; kc++)
      #pragma unroll
      for (int r = 0; r < 4; r++){
        int kw = (kc * 16 + g * 4 + r + 24) & 31;
        rw[qc][kc][r] = relw[((int64_t)bh * 1024 + qp_[qc]) * 32 + kw];
      }

  const unsigned short* vbase = vtb + (int64_t)bh * 64 * 1032;
  const unsigned short* kbase = kb + (int64_t)bh * 1032 * 64;
  const float* rhbase = relh + (int64_t)bh * 32 * 1024;

  // prefetch K fragments for first tile of this wave's chunk
  s8v kfc[2][2];
  #pragma unroll
  for (int kc = 0; kc < 2; kc++){
    int key = kt_lo * 32 + kc * 16 + l15; if (key > 1031) key = 1031;
    #pragma unroll
    for (int ch = 0; ch < 2; ch++)
      kfc[kc][ch] = *(const s8v*)(kbase + (int64_t)key * 64 + ch * 32 + g * 8);
  }

  for (int kt = kt_lo; kt < kt_hi; kt++){
    // prefetch next tile's K
    int ktn = (kt + 1 < kt_hi) ? kt + 1 : kt;
    s8v kfn[2][2];
    #pragma unroll
    for (int kc = 0; kc < 2; kc++){
      int key = ktn * 32 + kc * 16 + l15; if (key > 1031) key = 1031;
      #pragma unroll
      for (int ch = 0; ch < 2; ch++)
        kfn[kc][ch] = *(const s8v*)(kbase + (int64_t)key * 64 + ch * 32 + g * 8);
    }
    // V fragments (clamped so no row-overrun; clamped slots have zero weight)
    s4v vf[4][2];
    #pragma unroll
    for (int kc = 0; kc < 2; kc++){
      int kvo = kt * 32 + kc * 16 + g * 4; if (kvo > 1028) kvo = 1028;
      #pragma unroll
      for (int dc = 0; dc < 4; dc++)
        vf[dc][kc] = *(const s4v*)(vbase + (int64_t)(dc * 16 + l15) * 1032 + kvo);
    }
    // rel_h values
    int khA = kt - 1; if (khA < 0) khA = 0;
    int khB = kt; if (khB > 31) khB = 31;
    float rhA[2], rhB[2];
    #pragma unroll
    for (int qc = 0; qc < 2; qc++){
      rhA[qc] = rhbase[(int64_t)khA * 1024 + qp_[qc]];
      rhB[qc] = rhbase[(int64_t)khB * 1024 + qp_[qc]];
    }
    // QK^T (swapped: lane col = query)
    f4v sv[2][2];
    #pragma unroll
    for (int qc = 0; qc < 2; qc++)
      #pragma unroll
      for (int kc = 0; kc < 2; kc++){
        f4v s = {0.f, 0.f, 0.f, 0.f};
        s = mfma32(kfc[kc][0], qf[qc][0], s);
        s = mfma32(kfc[kc][1], qf[qc][1], s);
        sv[qc][kc] = s;
      }
    const bool anyprompt = (kt == 0);
    const bool anymask = (kt == 32);
    s4v bp[2][2];
    #pragma unroll
    for (int qc = 0; qc < 2; qc++){
      const bool qpr = qn_[qc] < 8;
      float pc[2][4];
      #pragma unroll
      for (int kc = 0; kc < 2; kc++)
        #pragma unroll
        for (int r = 0; r < 4; r++){
          int off = kc * 16 + g * 4 + r;
          float bias = qpr ? 0.f : ((off >= 8 ? rhB[qc] : rhA[qc]) + rw[qc][kc][r]);
          if (anyprompt && off < 8 && !qpr) bias = -144.269504f;
          float L = fmaf(sv[qc][kc][r], C1, bias);
          if (anymask && off >= 8) L = -3.0e38f;
          pc[kc][r] = L;
        }
      float tm = fmaxf(fmaxf(fmaxf(pc[0][0], pc[0][1]), fmaxf(pc[0][2], pc[0][3])),
                       fmaxf(fmaxf(pc[1][0], pc[1][1]), fmaxf(pc[1][2], pc[1][3])));
      tm = fmaxf(tm, __shfl_xor(tm, 16));
      tm = fmaxf(tm, __shfl_xor(tm, 32));
      if (!__all(tm <= mrun[qc])){
        float mnew = fmaxf(mrun[qc], tm);
        float alpha = exp2g(mrun[qc] - mnew);
        mrun[qc] = mnew;
        lrun[qc] *= alpha;
        #pragma unroll
        for (int dc = 0; dc < 4; dc++)
          of[dc][qc] = of[dc][qc] * alpha;
      }
      float m = mrun[qc];
      float p[8];
      #pragma unroll
      for (int kc = 0; kc < 2; kc++)
        #pragma unroll
        for (int r = 0; r < 4; r++)
          p[kc * 4 + r] = exp2g(pc[kc][r] - m);
      lrun[qc] += ((p[0]+p[1])+(p[2]+p[3])) + ((p[4]+p[5])+(p[6]+p[7]));  // per-lane partial
      bp[qc][0] = pack4(p[0], p[1], p[2], p[3]);
      bp[qc][1] = pack4(p[4], p[5], p[6], p[7]);
    }
    // PV
    #pragma unroll
    for (int dc = 0; dc < 4; dc++)
      #pragma unroll
      for (int kc = 0; kc < 2; kc++)
        #pragma unroll
        for (int qc = 0; qc < 2; qc++)
          of[dc][qc] = mfma16(vf[dc][kc], bp[qc][kc], of[dc][qc]);
    // roll prefetch
    #pragma unroll
    for (int kc = 0; kc < 2; kc++)
      #pragma unroll
      for (int ch = 0; ch < 2; ch++)
        kfc[kc][ch] = kfn[kc][ch];
  }

  // publish partials (waves 1..3)
  if (wid >= 1){
    #pragma unroll
    for (int dc = 0; dc < 4; dc++)
      #pragma unroll
      for (int qc = 0; qc < 2; qc++)
        *(f4v*)&ofs[wid - 1][dc][qc][lane][0] = of[dc][qc];
    #pragma unroll
    for (int qc = 0; qc < 2; qc++){
      mls[wid - 1][qc][lane][0] = mrun[qc];
      mls[wid - 1][qc][lane][1] = lrun[qc];
    }
  }
  __syncthreads();
  // merge + store (wave 0)
  if (wid == 0){
    #pragma unroll
    for (int qc = 0; qc < 2; qc++){
      int qn = qn_[qc];
      if (qn >= 1032) continue;
      float M = mrun[qc];
      #pragma unroll
      for (int w = 0; w < 3; w++) M = fmaxf(M, mls[w][qc][lane][0]);
      float a0 = exp2g(mrun[qc] - M);
      float lt = lrun[qc] * a0;
      f4v ot[4];
      #pragma unroll
      for (int dc = 0; dc < 4; dc++) ot[dc] = of[dc][qc] * a0;
      #pragma unroll
      for (int w = 0; w < 3; w++){
        float aw = exp2g(mls[w][qc][lane][0] - M);
        lt += mls[w][qc][lane][1] * aw;
        #pragma unroll
        for (int dc = 0; dc < 4; dc++)
          ot[dc] += (*(const f4v*)&ofs[w][dc][qc][lane][0]) * aw;
      }
      lt += __shfl_xor(lt, 16);
      lt += __shfl_xor(lt, 32);
      float inv = 1.0f / lt;
      unsigned short* dst = ao + ((int64_t)(b * 1032 + qn)) * 768 + head * 64;
      #pragma unroll
      for (int dc = 0; dc < 4; dc++){
        us4v pk = { f2bf(ot[dc][0] * inv), f2bf(ot[dc][1] * inv),
                    f2bf(ot[dc][2] * inv), f2bf(ot[dc][3] * inv) };
        *(us4v*)(dst + dc * 16 + g * 4) = pk;
      }
    }
  }
}

extern "C" void kernel_launch(void* const* d_in, const int* in_sizes, int n_in,
                              void* d_out, int out_size, void* d_ws, size_t ws_size,
                              hipStream_t stream)
{
  const float* x   = (const float*)d_in[0];
  const float* vp  = (const float*)d_in[1];
  const float* qw  = (const float*)d_in[2];
  const float* qbb = (const float*)d_in[3];
  const float* pw  = (const float*)d_in[4];
  const float* pb  = (const float*)d_in[5];
  const float* rph = (const float*)d_in[6];
  const float* rpw = (const float*)d_in[7];
  float* out = (float*)d_out;

  char* ws = (char*)d_ws;
  size_t off = 0;
  auto alloc = [&](size_t bytes) -> void* {
    void* p = ws + off;
    off = (off + bytes + 255) & ~(size_t)255;
    return p;
  };
  unsigned short* xs   = (unsigned short*)alloc((size_t)8256 * 768 * 2);
  unsigned short* Wt   = (unsigned short*)alloc((size_t)2304 * 768 * 2);
  unsigned short* Pt   = (unsigned short*)alloc((size_t)768 * 768 * 2);
  unsigned short* qbuf = (unsigned short*)alloc((size_t)96 * 1032 * 64 * 2);
  unsigned short* kbuf = (unsigned short*)alloc((size_t)96 * 1032 * 64 * 2);
  unsigned short* vtb  = (unsigned short*)alloc((size_t)96 * 64 * 1032 * 2 + 256);
  float* relh = (float*)alloc((size_t)96 * 32 * 1024 * 4);
  float* relw = (float*)alloc((size_t)96 * 1024 * 32 * 4);
  unsigned short* ao = xs;  // xs dead after QKV GEMM; reuse for attention output

  k_prep_xs<<<6192, 256, 0, stream>>>(x, vp, xs);
  k_prep_w<<<2304, 256, 0, stream>>>(qw, pw, Wt, Pt);
  k_gemm<0><<<dim3(18, 65), 256, 0, stream>>>(xs, Wt, qbb, 8256, 2304, 768,
                                              qbuf, kbuf, vtb, nullptr);
  k_rel_h<<<3072, 64, 0, stream>>>(qbuf, rph, relh);
  k_rel_w<<<3072, 64, 0, stream>>>(qbuf, rpw, relw);
  k_attn<<<3168, 256, 0, stream>>>(qbuf, kbuf, vtb, relh, relw, ao);
  k_gemm<1><<<dim3(6, 65), 256, 0, stream>>>(ao, Pt, pb, 8256, 768, 768,
                                             nullptr, nullptr, nullptr, out);
}

// Round 6
// 222.725 us; speedup vs baseline: 1.1432x; 1.0057x over previous
//
#include <hip/hip_runtime.h>
#include <stdint.h>

typedef __attribute__((ext_vector_type(8))) short s8v;
typedef __attribute__((ext_vector_type(4))) short s4v;
typedef __attribute__((ext_vector_type(4))) float f4v;
typedef __attribute__((ext_vector_type(4))) unsigned short us4v;
typedef __attribute__((ext_vector_type(4))) float f32x4v;

#define DEV static __device__ __forceinline__

#define L2E 1.44269504f

DEV unsigned short f2bf(float f){
  uint32_t x = __builtin_bit_cast(uint32_t, f);
  uint32_t r = x + 0x7fffu + ((x >> 16) & 1u);
  return (unsigned short)(r >> 16);
}

DEV float exp2g(float x){
#if __has_builtin(__builtin_amdgcn_exp2f)
  return __builtin_amdgcn_exp2f(x);
#else
  return exp2f(x);
#endif
}

// pack 4 f32 -> 4 bf16 (two v_cvt_pk_bf16_f32, RNE — same as f2bf)
DEV s4v pack4(float a, float b, float c, float d){
  uint32_t r0, r1;
  asm("v_cvt_pk_bf16_f32 %0, %1, %2" : "=v"(r0) : "v"(a), "v"(b));
  asm("v_cvt_pk_bf16_f32 %0, %1, %2" : "=v"(r1) : "v"(c), "v"(d));
  union { uint32_t u[2]; s4v s; } u; u.u[0] = r0; u.u[1] = r1; return u.s;
}

DEV f4v mfma32(s8v a, s8v b, f4v c){
  return __builtin_amdgcn_mfma_f32_16x16x32_bf16(a, b, c, 0, 0, 0);
}
DEV f4v mfma16(s4v a, s4v b, f4v c){
  return __builtin_amdgcn_mfma_f32_16x16x16bf16_1k(a, b, c, 0, 0, 0);
}

DEV void load_lds16(const void* g, void* l){
  __builtin_amdgcn_global_load_lds((const __attribute__((address_space(1))) uint32_t*)g,
                                   (__attribute__((address_space(3))) uint32_t*)l, 16, 0, 0);
}

// ---------------- prep: xs = concat(vp, x) -> bf16 ----------------
__global__ void k_prep_xs(const float* __restrict__ x, const float* __restrict__ vp,
                          unsigned short* __restrict__ xs){
  int64_t e = ((int64_t)blockIdx.x * 256 + threadIdx.x) * 4;
  int m = (int)(e / 768); int c = (int)(e % 768);
  int b = m / 1032, n = m % 1032;
  const float* src = (n < 8) ? (vp + ((int64_t)(b * 8 + n)) * 768 + c)
                             : (x  + ((int64_t)(b * 1024 + (n - 8))) * 768 + c);
  f32x4v v = *(const f32x4v*)src;
  us4v o = { f2bf(v[0]), f2bf(v[1]), f2bf(v[2]), f2bf(v[3]) };
  *(us4v*)(xs + e) = o;
}

// ---------------- prep: W transposes -> bf16 (LDS tile transpose) ----------------
// qw [768][2304] -> Wt [2304][768]; pw [768][768] -> Pt [768][768]
__global__ __launch_bounds__(256) void k_prep_w(const float* __restrict__ qw,
    const float* __restrict__ pw, unsigned short* __restrict__ Wt,
    unsigned short* __restrict__ Pt){
  __shared__ float tile[32][33];
  const int bid = blockIdx.x;
  const float* src; unsigned short* dst; int Cc, j0, k0;
  if (bid < 1728){
    int jt = bid % 72, kt = bid / 72;
    src = qw; dst = Wt; Cc = 2304; k0 = kt * 32; j0 = jt * 32;
  } else {
    int t2 = bid - 1728;
    int jt = t2 % 24, kt = t2 / 24;
    src = pw; dst = Pt; Cc = 768; k0 = kt * 32; j0 = jt * 32;
  }
  const int t = threadIdx.x;
  const int r = t >> 3, c4 = (t & 7) * 4;
  f32x4v v = *(const f32x4v*)(src + (int64_t)(k0 + r) * Cc + j0 + c4);
  tile[r][c4 + 0] = v[0]; tile[r][c4 + 1] = v[1];
  tile[r][c4 + 2] = v[2]; tile[r][c4 + 3] = v[3];
  __syncthreads();
  us4v o = { f2bf(tile[c4 + 0][r]), f2bf(tile[c4 + 1][r]),
             f2bf(tile[c4 + 2][r]), f2bf(tile[c4 + 3][r]) };
  *(us4v*)(dst + (int64_t)(j0 + r) * 768 + k0 + c4) = o;
}

// ---------------- GEMM: C = A[M,K] * Bt[N,K]^T + bias ----------------
template<int MODE>
__global__ __launch_bounds__(256) void k_gemm(
    const unsigned short* __restrict__ A, const unsigned short* __restrict__ Bt,
    const float* __restrict__ bias, int M, int N, int K,
    unsigned short* __restrict__ qb, unsigned short* __restrict__ kb,
    unsigned short* __restrict__ vtb, float* __restrict__ outp)
{
  __shared__ __align__(16) unsigned short At [128 * 32];
  __shared__ __align__(16) unsigned short Btl[128 * 32];
  const int tid = threadIdx.x, lane = tid & 63, wid = tid >> 6;
  const int mbase = blockIdx.y * 128, nbase = blockIdx.x * 128;
  const int wr = wid >> 1, wc = wid & 1;
  const int g = lane >> 4, l15 = lane & 15;
  const int l2 = lane >> 2, l3 = lane & 3;
  f4v acc[4][4] = {};

  int srow0 = wid * 16 + l2;
  int srow1 = 64 + wid * 16 + l2;
  int sg0 = l3 ^ ((srow0 >> 1) & 3);
  int sg1 = l3 ^ ((srow1 >> 1) & 3);
  int arow0 = mbase + srow0; if (arow0 >= M) arow0 = 0;
  int arow1 = mbase + srow1; if (arow1 >= M) arow1 = 0;
  const unsigned short* a0 = A  + (int64_t)arow0 * K + sg0 * 8;
  const unsigned short* a1 = A  + (int64_t)arow1 * K + sg1 * 8;
  const unsigned short* b0 = Bt + (int64_t)(nbase + srow0) * K + sg0 * 8;
  const unsigned short* b1 = Bt + (int64_t)(nbase + srow1) * K + sg1 * 8;
  unsigned short* lA0 = At  + wid * 16 * 32;
  unsigned short* lA1 = At  + (64 + wid * 16) * 32;
  unsigned short* lB0 = Btl + wid * 16 * 32;
  unsigned short* lB1 = Btl + (64 + wid * 16) * 32;

  for (int ks = 0; ks < K; ks += 32){
    load_lds16(a0 + ks, lA0);
    load_lds16(a1 + ks, lA1);
    load_lds16(b0 + ks, lB0);
    load_lds16(b1 + ks, lB1);
    __syncthreads();
    s8v af[4], bf[4];
    #pragma unroll
    for (int mc = 0; mc < 4; mc++){
      int row = wr * 64 + mc * 16 + l15;
      int o = (row * 64 + g * 16) ^ (((row >> 1) & 3) << 4);
      af[mc] = *(const s8v*)((const char*)At + o);
    }
    #pragma unroll
    for (int nc = 0; nc < 4; nc++){
      int row = wc * 64 + nc * 16 + l15;
      int o = (row * 64 + g * 16) ^ (((row >> 1) & 3) << 4);
      bf[nc] = *(const s8v*)((const char*)Btl + o);
    }
    #pragma unroll
    for (int mc = 0; mc < 4; mc++)
      #pragma unroll
      for (int nc = 0; nc < 4; nc++)
        acc[mc][nc] = mfma32(af[mc], bf[nc], acc[mc][nc]);
    __syncthreads();
  }

  if (MODE == 0){
    const int which = nbase / 768;
    const int head  = ((nbase % 768) >> 6) + wc;
    #pragma unroll
    for (int nc = 0; nc < 4; nc++){
      int j = nbase + wc * 64 + nc * 16 + l15;
      float bv = bias[j];
      int d = nc * 16 + l15;
      #pragma unroll
      for (int mc = 0; mc < 4; mc++){
        int m0 = mbase + wr * 64 + mc * 16 + g * 4;
        if (m0 >= M) continue;
        int b = m0 / 1032, n = m0 % 1032;
        int bh = b * 12 + head;
        if (which == 2){
          us4v pk = { f2bf(acc[mc][nc][0] + bv), f2bf(acc[mc][nc][1] + bv),
                      f2bf(acc[mc][nc][2] + bv), f2bf(acc[mc][nc][3] + bv) };
          *(us4v*)(vtb + ((int64_t)bh * 64 + d) * 1032 + n) = pk;
        } else {
          unsigned short* dst = (which == 0 ? qb : kb) + ((int64_t)bh * 1032 + n) * 64 + d;
          #pragma unroll
          for (int r = 0; r < 4; r++) dst[(int64_t)r * 64] = f2bf(acc[mc][nc][r] + bv);
        }
      }
    }
  } else {
    #pragma unroll
    for (int nc = 0; nc < 4; nc++){
      int j = nbase + wc * 64 + nc * 16 + l15;
      float bv = bias[j];
      #pragma unroll
      for (int mc = 0; mc < 4; mc++){
        int m0 = mbase + wr * 64 + mc * 16 + g * 4;
        if (m0 >= M) continue;
        int b = m0 / 1032, n0 = m0 % 1032;
        #pragma unroll
        for (int r = 0; r < 4; r++){
          int n = n0 + r;
          float v = acc[mc][nc][r] + bv;
          int64_t dst = (n < 8) ? (6291456LL + ((int64_t)(b * 8 + n)) * 768 + j)
                                : (((int64_t)(b * 1024 + (n - 8))) * 768 + j);
          outp[dst] = v;
        }
      }
    }
  }
}

// ---------------- rel_h: [bh][kh][qp] = (q . Rh) * log2e ----------------
__global__ __launch_bounds__(64) void k_rel_h(const unsigned short* __restrict__ qbuf,
    const float* __restrict__ rph, float* __restrict__ relh)
{
  const int lane = threadIdx.x;
  const int bh = blockIdx.x >> 5;
  const int qh = blockIdx.x & 31;
  const int g = lane >> 4, l15 = lane & 15;
  s8v qf[2][2];
  #pragma unroll
  for (int qc = 0; qc < 2; qc++){
    int n = qh * 32 + qc * 16 + l15 + 8;
    #pragma unroll
    for (int ch = 0; ch < 2; ch++)
      qf[qc][ch] = *(const s8v*)(qbuf + ((int64_t)bh * 1032 + n) * 64 + ch * 32 + g * 8);
  }
  s8v rf[2][2];
  #pragma unroll
  for (int kc = 0; kc < 2; kc++){
    int kh = kc * 16 + l15;
    #pragma unroll
    for (int ch = 0; ch < 2; ch++){
      const float* rp = rph + (int64_t)(qh - kh + 31) * 64 + ch * 32 + g * 8;
      f32x4v v0 = *(const f32x4v*)rp;
      f32x4v v1 = *(const f32x4v*)(rp + 4);
      s8v t = { (short)f2bf(v0[0]), (short)f2bf(v0[1]), (short)f2bf(v0[2]), (short)f2bf(v0[3]),
                (short)f2bf(v1[0]), (short)f2bf(v1[1]), (short)f2bf(v1[2]), (short)f2bf(v1[3]) };
      rf[kc][ch] = t;
    }
  }
  #pragma unroll
  for (int kc = 0; kc < 2; kc++)
    #pragma unroll
    for (int qc = 0; qc < 2; qc++){
      f4v d = {0.f, 0.f, 0.f, 0.f};
      d = mfma32(rf[kc][0], qf[qc][0], d);
      d = mfma32(rf[kc][1], qf[qc][1], d);
      #pragma unroll
      for (int r = 0; r < 4; r++)
        relh[((int64_t)bh * 32 + kc * 16 + g * 4 + r) * 1024 + qh * 32 + qc * 16 + l15] = d[r] * L2E;
    }
}

// ---------------- rel_w: [bh][qp][kw] = (q . Rw) * log2e ----------------
__global__ __launch_bounds__(64) void k_rel_w(const unsigned short* __restrict__ qbuf,
    const float* __restrict__ rpw, float* __restrict__ relw)
{
  const int lane = threadIdx.x;
  const int bh = blockIdx.x >> 5;
  const int qw = blockIdx.x & 31;
  const int g = lane >> 4, l15 = lane & 15;
  s8v qf[2][2];
  #pragma unroll
  for (int qc = 0; qc < 2; qc++){
    int qp = qw + 32 * (qc * 16 + l15);
    int n = qp + 8;
    #pragma unroll
    for (int ch = 0; ch < 2; ch++)
      qf[qc][ch] = *(const s8v*)(qbuf + ((int64_t)bh * 1032 + n) * 64 + ch * 32 + g * 8);
  }
  s8v wf[2][2];
  #pragma unroll
  for (int kc = 0; kc < 2; kc++){
    int kw = kc * 16 + l15;
    #pragma unroll
    for (int ch = 0; ch < 2; ch++){
      const float* rp = rpw + (int64_t)(qw - kw + 31) * 64 + ch * 32 + g * 8;
      f32x4v v0 = *(const f32x4v*)rp;
      f32x4v v1 = *(const f32x4v*)(rp + 4);
      s8v t = { (short)f2bf(v0[0]), (short)f2bf(v0[1]), (short)f2bf(v0[2]), (short)f2bf(v0[3]),
                (short)f2bf(v1[0]), (short)f2bf(v1[1]), (short)f2bf(v1[2]), (short)f2bf(v1[3]) };
      wf[kc][ch] = t;
    }
  }
  #pragma unroll
  for (int qc = 0; qc < 2; qc++)
    #pragma unroll
    for (int kc = 0; kc < 2; kc++){
      f4v d = {0.f, 0.f, 0.f, 0.f};
      d = mfma32(qf[qc][0], wf[kc][0], d);
      d = mfma32(qf[qc][1], wf[kc][1], d);
      #pragma unroll
      for (int r = 0; r < 4; r++){
        int qp = qw + 32 * (qc * 16 + g * 4 + r);
        relw[((int64_t)bh * 1024 + qp) * 32 + kc * 16 + l15] = d[r] * L2E;
      }
    }
}

// ---------------- flash attention, 4-way K-split, max-free softmax ----------------
// r5 skeleton + : (1) NO in-loop max (logits bounded |L|<~15 -> exp2 safe in f32;
// bf16/f32 precision is scale-invariant), so no fmax tree / no shfl / no branch /
// no rescale in the k-loop; linear cross-wave merge. (2) V and rel_h prefetched
// one tile ahead (K already was) -> no L2 latency in the dependency chain.
__global__ __launch_bounds__(256, 3) void k_attn(
    const unsigned short* __restrict__ qb, const unsigned short* __restrict__ kb,
    const unsigned short* __restrict__ vtb, const float* __restrict__ relh,
    const float* __restrict__ relw, unsigned short* __restrict__ ao)
{
  const int lane = threadIdx.x & 63, wid = threadIdx.x >> 6;
  const int wq = (blockIdx.x & 7) * 396 + (blockIdx.x >> 3);  // XCD swizzle (T1)
  const int bh = wq / 33;
  const int qt = wq % 33;
  const int qbase = qt * 32;
  const int g = lane >> 4, l15 = lane & 15;
  const int b = bh / 12, head = bh % 12;
  const float C1 = 0.125f * L2E;
  const float NEG = -144.269504f;   // exp2 -> 0

  __shared__ __align__(16) float ofs[3][4][2][64][4];  // 24 KB: waves 1..3 O-partials
  __shared__ float lsh[3][2][64];                      // 1.5 KB: l partials

  const int kt_lo = (wid == 0) ? 0 : 1 + wid * 8;      // {0, 9, 17, 25}
  const int kt_hi = 1 + (wid + 1) * 8;                 // {9, 17, 25, 33}

  f4v of[4][2] = {};
  float lrun[2] = {0.f, 0.f};
  int qn_[2], qp_[2];

  s8v qf[2][2];
  float rw[2][2][4];
  #pragma unroll
  for (int qc = 0; qc < 2; qc++){
    int qn = qbase + qc * 16 + l15;
    qn_[qc] = qn;
    int qcl = qn < 1032 ? qn : 1031;
    #pragma unroll
    for (int ch = 0; ch < 2; ch++)
      qf[qc][ch] = *(const s8v*)(qb + ((int64_t)bh * 1032 + qcl) * 64 + ch * 32 + g * 8);
    int qp = qn - 8; if (qp < 0) qp = 0; if (qp > 1023) qp = 1023;
    qp_[qc] = qp;
  }
  #pragma unroll
  for (int qc = 0; qc < 2; qc++)
    #pragma unroll
    for (int kc = 0; kc < 2; kc++)
      #pragma unroll
      for (int r = 0; r < 4; r++){
        int kw = (kc * 16 + g * 4 + r + 24) & 31;
        rw[qc][kc][r] = relw[((int64_t)bh * 1024 + qp_[qc]) * 32 + kw];
      }

  const unsigned short* vbase = vtb + (int64_t)bh * 64 * 1032;
  const unsigned short* kbase = kb + (int64_t)bh * 1032 * 64;
  const float* rhbase = relh + (int64_t)bh * 32 * 1024;

  // ---- prologue prefetch: K, V, rel_h for kt_lo ----
  s8v kfc[2][2];
  s4v vfc[4][2];
  float rhA[2], rhB[2];
  #pragma unroll
  for (int kc = 0; kc < 2; kc++){
    int key = kt_lo * 32 + kc * 16 + l15; if (key > 1031) key = 1031;
    #pragma unroll
    for (int ch = 0; ch < 2; ch++)
      kfc[kc][ch] = *(const s8v*)(kbase + (int64_t)key * 64 + ch * 32 + g * 8);
  }
  #pragma unroll
  for (int kc = 0; kc < 2; kc++){
    int kvo = kt_lo * 32 + kc * 16 + g * 4; if (kvo > 1028) kvo = 1028;
    #pragma unroll
    for (int dc = 0; dc < 4; dc++)
      vfc[dc][kc] = *(const s4v*)(vbase + (int64_t)(dc * 16 + l15) * 1032 + kvo);
  }
  {
    int khA = kt_lo - 1; if (khA < 0) khA = 0;
    #pragma unroll
    for (int qc = 0; qc < 2; qc++){
      rhA[qc] = rhbase[(int64_t)khA * 1024 + qp_[qc]];
      rhB[qc] = rhbase[(int64_t)kt_lo * 1024 + qp_[qc]];
    }
  }

  for (int kt = kt_lo; kt < kt_hi; kt++){
    // QK^T (swapped: lane col = query) using current K regs
    f4v sv[2][2];
    #pragma unroll
    for (int qc = 0; qc < 2; qc++)
      #pragma unroll
      for (int kc = 0; kc < 2; kc++){
        f4v s = {0.f, 0.f, 0.f, 0.f};
        s = mfma32(kfc[kc][0], qf[qc][0], s);
        s = mfma32(kfc[kc][1], qf[qc][1], s);
        sv[qc][kc] = s;
      }
    // prefetch next tile's K (last use of kfc was above)
    int ktn = kt + 1; if (ktn >= kt_hi) ktn = kt_hi - 1;
    #pragma unroll
    for (int kc = 0; kc < 2; kc++){
      int key = ktn * 32 + kc * 16 + l15; if (key > 1031) key = 1031;
      #pragma unroll
      for (int ch = 0; ch < 2; ch++)
        kfc[kc][ch] = *(const s8v*)(kbase + (int64_t)key * 64 + ch * 32 + g * 8);
    }
    // prefetch next tile's rel_h row (rhB(ktn) = rh[min(ktn,31)])
    float rhBn[2];
    {
      int khn = ktn; if (khn > 31) khn = 31;
      #pragma unroll
      for (int qc = 0; qc < 2; qc++)
        rhBn[qc] = rhbase[(int64_t)khn * 1024 + qp_[qc]];
    }

    const bool anyprompt = (kt == 0);
    const bool anymask = (kt == 32);
    s4v bp[2][2];
    #pragma unroll
    for (int qc = 0; qc < 2; qc++){
      const bool qpr = qn_[qc] < 8;
      float p[8];
      #pragma unroll
      for (int kc = 0; kc < 2; kc++)
        #pragma unroll
        for (int r = 0; r < 4; r++){
          int off = kc * 16 + g * 4 + r;
          float bias = qpr ? 0.f : ((off >= 8 ? rhB[qc] : rhA[qc]) + rw[qc][kc][r]);
          if (anyprompt && off < 8 && !qpr) bias = NEG;
          float L = fmaf(sv[qc][kc][r], C1, bias);
          if (anymask && off >= 8) L = NEG;
          p[kc * 4 + r] = exp2g(L);
        }
      lrun[qc] += ((p[0]+p[1])+(p[2]+p[3])) + ((p[4]+p[5])+(p[6]+p[7]));
      bp[qc][0] = pack4(p[0], p[1], p[2], p[3]);
      bp[qc][1] = pack4(p[4], p[5], p[6], p[7]);
    }
    // PV using current V regs
    #pragma unroll
    for (int dc = 0; dc < 4; dc++)
      #pragma unroll
      for (int kc = 0; kc < 2; kc++)
        #pragma unroll
        for (int qc = 0; qc < 2; qc++)
          of[dc][qc] = mfma16(vfc[dc][kc], bp[qc][kc], of[dc][qc]);
    // prefetch next tile's V (last use of vfc was above)
    #pragma unroll
    for (int kc = 0; kc < 2; kc++){
      int kvo = ktn * 32 + kc * 16 + g * 4; if (kvo > 1028) kvo = 1028;
      #pragma unroll
      for (int dc = 0; dc < 4; dc++)
        vfc[dc][kc] = *(const s4v*)(vbase + (int64_t)(dc * 16 + l15) * 1032 + kvo);
    }
    // roll rel_h carry
    #pragma unroll
    for (int qc = 0; qc < 2; qc++){
      rhA[qc] = rhB[qc];
      rhB[qc] = rhBn[qc];
    }
  }

  // publish partials (waves 1..3)
  if (wid >= 1){
    #pragma unroll
    for (int dc = 0; dc < 4; dc++)
      #pragma unroll
      for (int qc = 0; qc < 2; qc++)
        *(f4v*)&ofs[wid - 1][dc][qc][lane][0] = of[dc][qc];
    #pragma unroll
    for (int qc = 0; qc < 2; qc++)
      lsh[wid - 1][qc][lane] = lrun[qc];
  }
  __syncthreads();
  // merge + store (wave 0): linear sum (no max needed)
  if (wid == 0){
    #pragma unroll
    for (int qc = 0; qc < 2; qc++){
      int qn = qn_[qc];
      if (qn >= 1032) continue;
      float lt = lrun[qc] + lsh[0][qc][lane] + lsh[1][qc][lane] + lsh[2][qc][lane];
      lt += __shfl_xor(lt, 16);
      lt += __shfl_xor(lt, 32);
      float inv = 1.0f / lt;
      unsigned short* dst = ao + ((int64_t)(b * 1032 + qn)) * 768 + head * 64;
      #pragma unroll
      for (int dc = 0; dc < 4; dc++){
        f4v ot = of[dc][qc];
        ot += *(const f4v*)&ofs[0][dc][qc][lane][0];
        ot += *(const f4v*)&ofs[1][dc][qc][lane][0];
        ot += *(const f4v*)&ofs[2][dc][qc][lane][0];
        us4v pk = { f2bf(ot[0] * inv), f2bf(ot[1] * inv),
                    f2bf(ot[2] * inv), f2bf(ot[3] * inv) };
        *(us4v*)(dst + dc * 16 + g * 4) = pk;
      }
    }
  }
}

extern "C" void kernel_launch(void* const* d_in, const int* in_sizes, int n_in,
                              void* d_out, int out_size, void* d_ws, size_t ws_size,
                              hipStream_t stream)
{
  const float* x   = (const float*)d_in[0];
  const float* vp  = (const float*)d_in[1];
  const float* qw  = (const float*)d_in[2];
  const float* qbb = (const float*)d_in[3];
  const float* pw  = (const float*)d_in[4];
  const float* pb  = (const float*)d_in[5];
  const float* rph = (const float*)d_in[6];
  const float* rpw = (const float*)d_in[7];
  float* out = (float*)d_out;

  char* ws = (char*)d_ws;
  size_t off = 0;
  auto alloc = [&](size_t bytes) -> void* {
    void* p = ws + off;
    off = (off + bytes + 255) & ~(size_t)255;
    return p;
  };
  unsigned short* xs   = (unsigned short*)alloc((size_t)8256 * 768 * 2);
  unsigned short* Wt   = (unsigned short*)alloc((size_t)2304 * 768 * 2);
  unsigned short* Pt   = (unsigned short*)alloc((size_t)768 * 768 * 2);
  unsigned short* qbuf = (unsigned short*)alloc((size_t)96 * 1032 * 64 * 2);
  unsigned short* kbuf = (unsigned short*)alloc((size_t)96 * 1032 * 64 * 2);
  unsigned short* vtb  = (unsigned short*)alloc((size_t)96 * 64 * 1032 * 2 + 256);
  float* relh = (float*)alloc((size_t)96 * 32 * 1024 * 4);
  float* relw = (float*)alloc((size_t)96 * 1024 * 32 * 4);
  unsigned short* ao = xs;  // xs dead after QKV GEMM; reuse for attention output

  k_prep_xs<<<6192, 256, 0, stream>>>(x, vp, xs);
  k_prep_w<<<2304, 256, 0, stream>>>(qw, pw, Wt, Pt);
  k_gemm<0><<<dim3(18, 65), 256, 0, stream>>>(xs, Wt, qbb, 8256, 2304, 768,
                                              qbuf, kbuf, vtb, nullptr);
  k_rel_h<<<3072, 64, 0, stream>>>(qbuf, rph, relh);
  k_rel_w<<<3072, 64, 0, stream>>>(qbuf, rpw, relw);
  k_attn<<<3168, 256, 0, stream>>>(qbuf, kbuf, vtb, relh, relw, ao);
  k_gemm<1><<<dim3(6, 65), 256, 0, stream>>>(ao, Pt, pb, 8256, 768, 768,
                                             nullptr, nullptr, nullptr, out);
}

// Round 7
// 174.169 us; speedup vs baseline: 1.4619x; 1.2788x over previous
//
#include <hip/hip_runtime.h>
#include <stdint.h>

typedef __attribute__((ext_vector_type(8))) short s8v;
typedef __attribute__((ext_vector_type(4))) short s4v;
typedef __attribute__((ext_vector_type(4))) float f4v;
typedef __attribute__((ext_vector_type(4))) unsigned short us4v;
typedef __attribute__((ext_vector_type(4))) float f32x4v;

#define DEV static __device__ __forceinline__

#define L2E 1.44269504f

DEV unsigned short f2bf(float f){
  uint32_t x = __builtin_bit_cast(uint32_t, f);
  uint32_t r = x + 0x7fffu + ((x >> 16) & 1u);
  return (unsigned short)(r >> 16);
}

DEV float exp2g(float x){
#if __has_builtin(__builtin_amdgcn_exp2f)
  return __builtin_amdgcn_exp2f(x);
#else
  return exp2f(x);
#endif
}

// pack 4 f32 -> 4 bf16 (two v_cvt_pk_bf16_f32, RNE — same as f2bf)
DEV s4v pack4(float a, float b, float c, float d){
  uint32_t r0, r1;
  asm("v_cvt_pk_bf16_f32 %0, %1, %2" : "=v"(r0) : "v"(a), "v"(b));
  asm("v_cvt_pk_bf16_f32 %0, %1, %2" : "=v"(r1) : "v"(c), "v"(d));
  union { uint32_t u[2]; s4v s; } u; u.u[0] = r0; u.u[1] = r1; return u.s;
}

DEV f4v mfma32(s8v a, s8v b, f4v c){
  return __builtin_amdgcn_mfma_f32_16x16x32_bf16(a, b, c, 0, 0, 0);
}
DEV f4v mfma16(s4v a, s4v b, f4v c){
  return __builtin_amdgcn_mfma_f32_16x16x16bf16_1k(a, b, c, 0, 0, 0);
}

DEV void load_lds16(const void* g, void* l){
  __builtin_amdgcn_global_load_lds((const __attribute__((address_space(1))) uint32_t*)g,
                                   (__attribute__((address_space(3))) uint32_t*)l, 16, 0, 0);
}

// ---------------- prep: xs = concat(vp, x) -> bf16 ----------------
__global__ void k_prep_xs(const float* __restrict__ x, const float* __restrict__ vp,
                          unsigned short* __restrict__ xs){
  int64_t e = ((int64_t)blockIdx.x * 256 + threadIdx.x) * 4;
  int m = (int)(e / 768); int c = (int)(e % 768);
  int b = m / 1032, n = m % 1032;
  const float* src = (n < 8) ? (vp + ((int64_t)(b * 8 + n)) * 768 + c)
                             : (x  + ((int64_t)(b * 1024 + (n - 8))) * 768 + c);
  f32x4v v = *(const f32x4v*)src;
  us4v o = { f2bf(v[0]), f2bf(v[1]), f2bf(v[2]), f2bf(v[3]) };
  *(us4v*)(xs + e) = o;
}

// ---------------- prep: W transposes -> bf16 (LDS tile transpose) ----------------
__global__ __launch_bounds__(256) void k_prep_w(const float* __restrict__ qw,
    const float* __restrict__ pw, unsigned short* __restrict__ Wt,
    unsigned short* __restrict__ Pt){
  __shared__ float tile[32][33];
  const int bid = blockIdx.x;
  const float* src; unsigned short* dst; int Cc, j0, k0;
  if (bid < 1728){
    int jt = bid % 72, kt = bid / 72;
    src = qw; dst = Wt; Cc = 2304; k0 = kt * 32; j0 = jt * 32;
  } else {
    int t2 = bid - 1728;
    int jt = t2 % 24, kt = t2 / 24;
    src = pw; dst = Pt; Cc = 768; k0 = kt * 32; j0 = jt * 32;
  }
  const int t = threadIdx.x;
  const int r = t >> 3, c4 = (t & 7) * 4;
  f32x4v v = *(const f32x4v*)(src + (int64_t)(k0 + r) * Cc + j0 + c4);
  tile[r][c4 + 0] = v[0]; tile[r][c4 + 1] = v[1];
  tile[r][c4 + 2] = v[2]; tile[r][c4 + 3] = v[3];
  __syncthreads();
  us4v o = { f2bf(tile[c4 + 0][r]), f2bf(tile[c4 + 1][r]),
             f2bf(tile[c4 + 2][r]), f2bf(tile[c4 + 3][r]) };
  *(us4v*)(dst + (int64_t)(j0 + r) * 768 + k0 + c4) = o;
}

// ---------------- GEMM: C = A[M,K] * Bt[N,K]^T + bias ----------------
template<int MODE>
__global__ __launch_bounds__(256) void k_gemm(
    const unsigned short* __restrict__ A, const unsigned short* __restrict__ Bt,
    const float* __restrict__ bias, int M, int N, int K,
    unsigned short* __restrict__ qb, unsigned short* __restrict__ kb,
    unsigned short* __restrict__ vtb, float* __restrict__ outp)
{
  __shared__ __align__(16) unsigned short At [128 * 32];
  __shared__ __align__(16) unsigned short Btl[128 * 32];
  const int tid = threadIdx.x, lane = tid & 63, wid = tid >> 6;
  const int mbase = blockIdx.y * 128, nbase = blockIdx.x * 128;
  const int wr = wid >> 1, wc = wid & 1;
  const int g = lane >> 4, l15 = lane & 15;
  const int l2 = lane >> 2, l3 = lane & 3;
  f4v acc[4][4] = {};

  int srow0 = wid * 16 + l2;
  int srow1 = 64 + wid * 16 + l2;
  int sg0 = l3 ^ ((srow0 >> 1) & 3);
  int sg1 = l3 ^ ((srow1 >> 1) & 3);
  int arow0 = mbase + srow0; if (arow0 >= M) arow0 = 0;
  int arow1 = mbase + srow1; if (arow1 >= M) arow1 = 0;
  const unsigned short* a0 = A  + (int64_t)arow0 * K + sg0 * 8;
  const unsigned short* a1 = A  + (int64_t)arow1 * K + sg1 * 8;
  const unsigned short* b0 = Bt + (int64_t)(nbase + srow0) * K + sg0 * 8;
  const unsigned short* b1 = Bt + (int64_t)(nbase + srow1) * K + sg1 * 8;
  unsigned short* lA0 = At  + wid * 16 * 32;
  unsigned short* lA1 = At  + (64 + wid * 16) * 32;
  unsigned short* lB0 = Btl + wid * 16 * 32;
  unsigned short* lB1 = Btl + (64 + wid * 16) * 32;

  for (int ks = 0; ks < K; ks += 32){
    load_lds16(a0 + ks, lA0);
    load_lds16(a1 + ks, lA1);
    load_lds16(b0 + ks, lB0);
    load_lds16(b1 + ks, lB1);
    __syncthreads();
    s8v af[4], bf[4];
    #pragma unroll
    for (int mc = 0; mc < 4; mc++){
      int row = wr * 64 + mc * 16 + l15;
      int o = (row * 64 + g * 16) ^ (((row >> 1) & 3) << 4);
      af[mc] = *(const s8v*)((const char*)At + o);
    }
    #pragma unroll
    for (int nc = 0; nc < 4; nc++){
      int row = wc * 64 + nc * 16 + l15;
      int o = (row * 64 + g * 16) ^ (((row >> 1) & 3) << 4);
      bf[nc] = *(const s8v*)((const char*)Btl + o);
    }
    #pragma unroll
    for (int mc = 0; mc < 4; mc++)
      #pragma unroll
      for (int nc = 0; nc < 4; nc++)
        acc[mc][nc] = mfma32(af[mc], bf[nc], acc[mc][nc]);
    __syncthreads();
  }

  if (MODE == 0){
    const int which = nbase / 768;
    const int head  = ((nbase % 768) >> 6) + wc;
    #pragma unroll
    for (int nc = 0; nc < 4; nc++){
      int j = nbase + wc * 64 + nc * 16 + l15;
      float bv = bias[j];
      int d = nc * 16 + l15;
      #pragma unroll
      for (int mc = 0; mc < 4; mc++){
        int m0 = mbase + wr * 64 + mc * 16 + g * 4;
        if (m0 >= M) continue;
        int b = m0 / 1032, n = m0 % 1032;
        int bh = b * 12 + head;
        if (which == 2){
          us4v pk = { f2bf(acc[mc][nc][0] + bv), f2bf(acc[mc][nc][1] + bv),
                      f2bf(acc[mc][nc][2] + bv), f2bf(acc[mc][nc][3] + bv) };
          *(us4v*)(vtb + ((int64_t)bh * 64 + d) * 1032 + n) = pk;
        } else {
          unsigned short* dst = (which == 0 ? qb : kb) + ((int64_t)bh * 1032 + n) * 64 + d;
          #pragma unroll
          for (int r = 0; r < 4; r++) dst[(int64_t)r * 64] = f2bf(acc[mc][nc][r] + bv);
        }
      }
    }
  } else {
    #pragma unroll
    for (int nc = 0; nc < 4; nc++){
      int j = nbase + wc * 64 + nc * 16 + l15;
      float bv = bias[j];
      #pragma unroll
      for (int mc = 0; mc < 4; mc++){
        int m0 = mbase + wr * 64 + mc * 16 + g * 4;
        if (m0 >= M) continue;
        int b = m0 / 1032, n0 = m0 % 1032;
        #pragma unroll
        for (int r = 0; r < 4; r++){
          int n = n0 + r;
          float v = acc[mc][nc][r] + bv;
          int64_t dst = (n < 8) ? (6291456LL + ((int64_t)(b * 8 + n)) * 768 + j)
                                : (((int64_t)(b * 1024 + (n - 8))) * 768 + j);
          outp[dst] = v;
        }
      }
    }
  }
}

// ---------------- rel_h: [bh][kh][qp] = (q . Rh) * log2e ----------------
__global__ __launch_bounds__(64) void k_rel_h(const unsigned short* __restrict__ qbuf,
    const float* __restrict__ rph, float* __restrict__ relh)
{
  const int lane = threadIdx.x;
  const int bh = blockIdx.x >> 5;
  const int qh = blockIdx.x & 31;
  const int g = lane >> 4, l15 = lane & 15;
  s8v qf[2][2];
  #pragma unroll
  for (int qc = 0; qc < 2; qc++){
    int n = qh * 32 + qc * 16 + l15 + 8;
    #pragma unroll
    for (int ch = 0; ch < 2; ch++)
      qf[qc][ch] = *(const s8v*)(qbuf + ((int64_t)bh * 1032 + n) * 64 + ch * 32 + g * 8);
  }
  s8v rf[2][2];
  #pragma unroll
  for (int kc = 0; kc < 2; kc++){
    int kh = kc * 16 + l15;
    #pragma unroll
    for (int ch = 0; ch < 2; ch++){
      const float* rp = rph + (int64_t)(qh - kh + 31) * 64 + ch * 32 + g * 8;
      f32x4v v0 = *(const f32x4v*)rp;
      f32x4v v1 = *(const f32x4v*)(rp + 4);
      s8v t = { (short)f2bf(v0[0]), (short)f2bf(v0[1]), (short)f2bf(v0[2]), (short)f2bf(v0[3]),
                (short)f2bf(v1[0]), (short)f2bf(v1[1]), (short)f2bf(v1[2]), (short)f2bf(v1[3]) };
      rf[kc][ch] = t;
    }
  }
  #pragma unroll
  for (int kc = 0; kc < 2; kc++)
    #pragma unroll
    for (int qc = 0; qc < 2; qc++){
      f4v d = {0.f, 0.f, 0.f, 0.f};
      d = mfma32(rf[kc][0], qf[qc][0], d);
      d = mfma32(rf[kc][1], qf[qc][1], d);
      #pragma unroll
      for (int r = 0; r < 4; r++)
        relh[((int64_t)bh * 32 + kc * 16 + g * 4 + r) * 1024 + qh * 32 + qc * 16 + l15] = d[r] * L2E;
    }
}

// ---------------- rel_w: [bh][qp][kw] = (q . Rw) * log2e ----------------
__global__ __launch_bounds__(64) void k_rel_w(const unsigned short* __restrict__ qbuf,
    const float* __restrict__ rpw, float* __restrict__ relw)
{
  const int lane = threadIdx.x;
  const int bh = blockIdx.x >> 5;
  const int qw = blockIdx.x & 31;
  const int g = lane >> 4, l15 = lane & 15;
  s8v qf[2][2];
  #pragma unroll
  for (int qc = 0; qc < 2; qc++){
    int qp = qw + 32 * (qc * 16 + l15);
    int n = qp + 8;
    #pragma unroll
    for (int ch = 0; ch < 2; ch++)
      qf[qc][ch] = *(const s8v*)(qbuf + ((int64_t)bh * 1032 + n) * 64 + ch * 32 + g * 8);
  }
  s8v wf[2][2];
  #pragma unroll
  for (int kc = 0; kc < 2; kc++){
    int kw = kc * 16 + l15;
    #pragma unroll
    for (int ch = 0; ch < 2; ch++){
      const float* rp = rpw + (int64_t)(qw - kw + 31) * 64 + ch * 32 + g * 8;
      f32x4v v0 = *(const f32x4v*)rp;
      f32x4v v1 = *(const f32x4v*)(rp + 4);
      s8v t = { (short)f2bf(v0[0]), (short)f2bf(v0[1]), (short)f2bf(v0[2]), (short)f2bf(v0[3]),
                (short)f2bf(v1[0]), (short)f2bf(v1[1]), (short)f2bf(v1[2]), (short)f2bf(v1[3]) };
      wf[kc][ch] = t;
    }
  }
  #pragma unroll
  for (int qc = 0; qc < 2; qc++)
    #pragma unroll
    for (int kc = 0; kc < 2; kc++){
      f4v d = {0.f, 0.f, 0.f, 0.f};
      d = mfma32(qf[qc][0], wf[kc][0], d);
      d = mfma32(qf[qc][1], wf[kc][1], d);
      #pragma unroll
      for (int r = 0; r < 4; r++){
        int qp = qw + 32 * (qc * 16 + g * 4 + r);
        relw[((int64_t)bh * 1024 + qp) * 32 + kc * 16 + l15] = d[r] * L2E;
      }
    }
}

// ---------------- flash attention, LDS-staged K/V shared by 4 waves ----------------
// Block = (bh, group of 4 q-tiles); each wave owns one q-tile and iterates over
// ALL 33 k-tiles. Per k-tile, K (32x64 bf16, 4KB) and V^T (64x32 bf16, 4KB) are
// staged ONCE into LDS via global_load_lds (coalesced; source pre-swizzled so
// swizzled ds_reads are conflict-floor), then all 4 waves read fragments from
// LDS. m97 single-buffer structure: stage -> barrier -> compute -> barrier.
// Softmax core = verified max-free exp2 (round 6). No cross-wave merge needed.
__global__ __launch_bounds__(256, 3) void k_attn(
    const unsigned short* __restrict__ qb, const unsigned short* __restrict__ kb,
    const unsigned short* __restrict__ vtb, const float* __restrict__ relh,
    const float* __restrict__ relw, unsigned short* __restrict__ ao)
{
  const int lane = threadIdx.x & 63, wid = threadIdx.x >> 6;
  // XCD-bijective swizzle: 864 = 8 * 108
  const int wq = (blockIdx.x & 7) * 108 + (blockIdx.x >> 3);
  const int bh = wq / 9;
  const int qg = wq % 9;
  int qt = qg * 4 + wid; if (qt > 32) qt = 32;   // dup waves write identical data
  const int qbase = qt * 32;
  const int g = lane >> 4, l15 = lane & 15;
  const int b = bh / 12, head = bh % 12;
  const float C1 = 0.125f * L2E;
  const float NEG = -144.269504f;   // exp2 -> 0

  __shared__ __align__(16) unsigned short Kl[32 * 64];  // 4KB, row=128B, slot^=(r&7)
  __shared__ __align__(16) unsigned short Vl[64 * 32];  // 4KB, row=64B,  slot^=((d^(d>>2))&3)

  f4v of[4][2] = {};
  float lrun[2] = {0.f, 0.f};
  int qn_[2], qp_[2];

  s8v qf[2][2];
  float rw[2][2][4];
  #pragma unroll
  for (int qc = 0; qc < 2; qc++){
    int qn = qbase + qc * 16 + l15;
    qn_[qc] = qn;
    int qcl = qn < 1032 ? qn : 1031;
    #pragma unroll
    for (int ch = 0; ch < 2; ch++)
      qf[qc][ch] = *(const s8v*)(qb + ((int64_t)bh * 1032 + qcl) * 64 + ch * 32 + g * 8);
    int qp = qn - 8; if (qp < 0) qp = 0; if (qp > 1023) qp = 1023;
    qp_[qc] = qp;
  }
  #pragma unroll
  for (int qc = 0; qc < 2; qc++)
    #pragma unroll
    for (int kc = 0; kc < 2; kc++)
      #pragma unroll
      for (int r = 0; r < 4; r++){
        int kw = (kc * 16 + g * 4 + r + 24) & 31;
        rw[qc][kc][r] = relw[((int64_t)bh * 1024 + qp_[qc]) * 32 + kw];
      }

  const char* kbb = (const char*)(kb + (int64_t)bh * 1032 * 64);
  const char* vbb = (const char*)(vtb + (int64_t)bh * 64 * 1032);
  const float* rhbase = relh + (int64_t)bh * 32 * 1024;

  // staging geometry (per wave; lane's LDS dest = base + lane*16, HW-linear)
  const int krow_l = (lane >> 3);                    // 0..7 within wave's 8 rows
  const int kcol_s = ((lane & 7) ^ krow_l) << 4;     // pre-swizzled col byte
  const int vd_l   = (lane >> 2);                    // 0..15 within wave's 16 rows
  const int vslot  = ((lane & 3) ^ ((lane >> 2) ^ (lane >> 4)) & 3);
  char* kdst = (char*)Kl + wid * 1024;
  char* vdst = (char*)Vl + wid * 1024;
  const int vsw = (l15 ^ (l15 >> 2)) & 3;            // read-side V swizzle

  for (int kt = 0; kt < 33; kt++){
    // ---- stage tile kt (4 waves cooperatively; clamped sources stay finite) ----
    {
      int gr = kt * 32 + wid * 8 + krow_l; if (gr > 1031) gr = 1031;
      load_lds16(kbb + (int64_t)gr * 128 + kcol_s, kdst);
      int d = wid * 16 + vd_l;
      int scol = kt * 64 + (vslot << 4); if (scol > 2048) scol = 2048;
      load_lds16(vbb + (int64_t)d * 2064 + scol, vdst);
    }
    __syncthreads();

    // ---- fragments from LDS ----
    s8v kf[2][2];
    #pragma unroll
    for (int kc = 0; kc < 2; kc++){
      int roff = (kc * 16 + l15) << 7;
      #pragma unroll
      for (int ch = 0; ch < 2; ch++)
        kf[kc][ch] = *(const s8v*)((const char*)Kl + roff + ((((ch << 2) + g) ^ (l15 & 7)) << 4));
    }
    s4v vf[4][2];
    #pragma unroll
    for (int dc = 0; dc < 4; dc++){
      int doff = ((dc * 16 + l15) << 6) + ((g & 1) << 3);
      #pragma unroll
      for (int kc = 0; kc < 2; kc++)
        vf[dc][kc] = *(const s4v*)((const char*)Vl + doff + ((((kc << 1) + (g >> 1)) ^ vsw) << 4));
    }
    // rel_h rows
    int khA = kt - 1; if (khA < 0) khA = 0;
    int khB = kt; if (khB > 31) khB = 31;
    float rhA[2], rhB[2];
    #pragma unroll
    for (int qc = 0; qc < 2; qc++){
      rhA[qc] = rhbase[(int64_t)khA * 1024 + qp_[qc]];
      rhB[qc] = rhbase[(int64_t)khB * 1024 + qp_[qc]];
    }

    // ---- QK^T (swapped: lane col = query) ----
    f4v sv[2][2];
    #pragma unroll
    for (int qc = 0; qc < 2; qc++)
      #pragma unroll
      for (int kc = 0; kc < 2; kc++){
        f4v s = {0.f, 0.f, 0.f, 0.f};
        s = mfma32(kf[kc][0], qf[qc][0], s);
        s = mfma32(kf[kc][1], qf[qc][1], s);
        sv[qc][kc] = s;
      }

    const bool anyprompt = (kt == 0);
    const bool anymask = (kt == 32);
    s4v bp[2][2];
    #pragma unroll
    for (int qc = 0; qc < 2; qc++){
      const bool qpr = qn_[qc] < 8;
      float p[8];
      #pragma unroll
      for (int kc = 0; kc < 2; kc++)
        #pragma unroll
        for (int r = 0; r < 4; r++){
          int off = kc * 16 + g * 4 + r;
          float bias = qpr ? 0.f : ((off >= 8 ? rhB[qc] : rhA[qc]) + rw[qc][kc][r]);
          if (anyprompt && off < 8 && !qpr) bias = NEG;
          float L = fmaf(sv[qc][kc][r], C1, bias);
          if (anymask && off >= 8) L = NEG;
          p[kc * 4 + r] = exp2g(L);
        }
      lrun[qc] += ((p[0]+p[1])+(p[2]+p[3])) + ((p[4]+p[5])+(p[6]+p[7]));
      bp[qc][0] = pack4(p[0], p[1], p[2], p[3]);
      bp[qc][1] = pack4(p[4], p[5], p[6], p[7]);
    }
    // ---- PV ----
    #pragma unroll
    for (int dc = 0; dc < 4; dc++)
      #pragma unroll
      for (int kc = 0; kc < 2; kc++)
        #pragma unroll
        for (int qc = 0; qc < 2; qc++)
          of[dc][qc] = mfma16(vf[dc][kc], bp[qc][kc], of[dc][qc]);

    __syncthreads();   // all waves done reading before next stage overwrites
  }

  // ---- epilogue: l-reduce across g-groups, normalize, store ----
  #pragma unroll
  for (int qc = 0; qc < 2; qc++){
    int qn = qn_[qc];
    if (qn >= 1032) continue;
    float lt = lrun[qc];
    lt += __shfl_xor(lt, 16);
    lt += __shfl_xor(lt, 32);
    float inv = 1.0f / lt;
    unsigned short* dst = ao + ((int64_t)(b * 1032 + qn)) * 768 + head * 64;
    #pragma unroll
    for (int dc = 0; dc < 4; dc++){
      us4v pk = { f2bf(of[dc][qc][0] * inv), f2bf(of[dc][qc][1] * inv),
                  f2bf(of[dc][qc][2] * inv), f2bf(of[dc][qc][3] * inv) };
      *(us4v*)(dst + dc * 16 + g * 4) = pk;
    }
  }
}

extern "C" void kernel_launch(void* const* d_in, const int* in_sizes, int n_in,
                              void* d_out, int out_size, void* d_ws, size_t ws_size,
                              hipStream_t stream)
{
  const float* x   = (const float*)d_in[0];
  const float* vp  = (const float*)d_in[1];
  const float* qw  = (const float*)d_in[2];
  const float* qbb = (const float*)d_in[3];
  const float* pw  = (const float*)d_in[4];
  const float* pb  = (const float*)d_in[5];
  const float* rph = (const float*)d_in[6];
  const float* rpw = (const float*)d_in[7];
  float* out = (float*)d_out;

  char* ws = (char*)d_ws;
  size_t off = 0;
  auto alloc = [&](size_t bytes) -> void* {
    void* p = ws + off;
    off = (off + bytes + 255) & ~(size_t)255;
    return p;
  };
  unsigned short* xs   = (unsigned short*)alloc((size_t)8256 * 768 * 2);
  unsigned short* Wt   = (unsigned short*)alloc((size_t)2304 * 768 * 2);
  unsigned short* Pt   = (unsigned short*)alloc((size_t)768 * 768 * 2);
  unsigned short* qbuf = (unsigned short*)alloc((size_t)96 * 1032 * 64 * 2);
  unsigned short* kbuf = (unsigned short*)alloc((size_t)96 * 1032 * 64 * 2 + 4096);
  unsigned short* vtb  = (unsigned short*)alloc((size_t)96 * 64 * 1032 * 2 + 4096);
  float* relh = (float*)alloc((size_t)96 * 32 * 1024 * 4);
  float* relw = (float*)alloc((size_t)96 * 1024 * 32 * 4);
  unsigned short* ao = xs;  // xs dead after QKV GEMM; reuse for attention output

  k_prep_xs<<<6192, 256, 0, stream>>>(x, vp, xs);
  k_prep_w<<<2304, 256, 0, stream>>>(qw, pw, Wt, Pt);
  k_gemm<0><<<dim3(18, 65), 256, 0, stream>>>(xs, Wt, qbb, 8256, 2304, 768,
                                              qbuf, kbuf, vtb, nullptr);
  k_rel_h<<<3072, 64, 0, stream>>>(qbuf, rph, relh);
  k_rel_w<<<3072, 64, 0, stream>>>(qbuf, rpw, relw);
  k_attn<<<864, 256, 0, stream>>>(qbuf, kbuf, vtb, relh, relw, ao);
  k_gemm<1><<<dim3(6, 65), 256, 0, stream>>>(ao, Pt, pb, 8256, 768, 768,
                                             nullptr, nullptr, nullptr, out);
}

// Round 11
// 168.578 us; speedup vs baseline: 1.5104x; 1.0332x over previous
//
#include <hip/hip_runtime.h>
#include <stdint.h>

typedef __attribute__((ext_vector_type(8))) short s8v;
typedef __attribute__((ext_vector_type(4))) short s4v;
typedef __attribute__((ext_vector_type(4))) float f4v;
typedef __attribute__((ext_vector_type(4))) unsigned short us4v;
typedef __attribute__((ext_vector_type(4))) float f32x4v;

#define DEV static __device__ __forceinline__

#define L2E 1.44269504f

DEV unsigned short f2bf(float f){
  uint32_t x = __builtin_bit_cast(uint32_t, f);
  uint32_t r = x + 0x7fffu + ((x >> 16) & 1u);
  return (unsigned short)(r >> 16);
}

DEV float exp2g(float x){
#if __has_builtin(__builtin_amdgcn_exp2f)
  return __builtin_amdgcn_exp2f(x);
#else
  return exp2f(x);
#endif
}

// pack 4 f32 -> 4 bf16 (two v_cvt_pk_bf16_f32, RNE — same as f2bf)
DEV s4v pack4(float a, float b, float c, float d){
  uint32_t r0, r1;
  asm("v_cvt_pk_bf16_f32 %0, %1, %2" : "=v"(r0) : "v"(a), "v"(b));
  asm("v_cvt_pk_bf16_f32 %0, %1, %2" : "=v"(r1) : "v"(c), "v"(d));
  union { uint32_t u[2]; s4v s; } u; u.u[0] = r0; u.u[1] = r1; return u.s;
}

DEV f4v mfma32(s8v a, s8v b, f4v c){
  return __builtin_amdgcn_mfma_f32_16x16x32_bf16(a, b, c, 0, 0, 0);
}
DEV f4v mfma16(s4v a, s4v b, f4v c){
  return __builtin_amdgcn_mfma_f32_16x16x16bf16_1k(a, b, c, 0, 0, 0);
}

DEV void load_lds16(const void* g, void* l){
  __builtin_amdgcn_global_load_lds((const __attribute__((address_space(1))) uint32_t*)g,
                                   (__attribute__((address_space(3))) uint32_t*)l, 16, 0, 0);
}

// ---------------- fused prep: xs concat + W transposes ----------------
__global__ __launch_bounds__(256) void k_prep(const float* __restrict__ x,
    const float* __restrict__ vp, const float* __restrict__ qw,
    const float* __restrict__ pw, unsigned short* __restrict__ xs,
    unsigned short* __restrict__ Wt, unsigned short* __restrict__ Pt){
  __shared__ float tile[32][33];
  const int bid = blockIdx.x;
  if (bid < 6192){
    // xs = concat(vp, x) -> bf16  (verbatim r7 k_prep_xs math)
    int64_t e = ((int64_t)bid * 256 + threadIdx.x) * 4;
    int m = (int)(e / 768); int c = (int)(e % 768);
    int b = m / 1032, n = m % 1032;
    const float* src = (n < 8) ? (vp + ((int64_t)(b * 8 + n)) * 768 + c)
                               : (x  + ((int64_t)(b * 1024 + (n - 8))) * 768 + c);
    f32x4v v = *(const f32x4v*)src;
    us4v o = { f2bf(v[0]), f2bf(v[1]), f2bf(v[2]), f2bf(v[3]) };
    *(us4v*)(xs + e) = o;
    return;
  }
  // W transposes via LDS tile  (verbatim r7 k_prep_w math)
  const int wb = bid - 6192;
  const float* src; unsigned short* dst; int Cc, j0, k0;
  if (wb < 1728){
    int jt = wb % 72, kt = wb / 72;
    src = qw; dst = Wt; Cc = 2304; k0 = kt * 32; j0 = jt * 32;
  } else {
    int t2 = wb - 1728;
    int jt = t2 % 24, kt = t2 / 24;
    src = pw; dst = Pt; Cc = 768; k0 = kt * 32; j0 = jt * 32;
  }
  const int t = threadIdx.x;
  const int r = t >> 3, c4 = (t & 7) * 4;
  f32x4v v = *(const f32x4v*)(src + (int64_t)(k0 + r) * Cc + j0 + c4);
  tile[r][c4 + 0] = v[0]; tile[r][c4 + 1] = v[1];
  tile[r][c4 + 2] = v[2]; tile[r][c4 + 3] = v[3];
  __syncthreads();
  us4v o = { f2bf(tile[c4 + 0][r]), f2bf(tile[c4 + 1][r]),
             f2bf(tile[c4 + 2][r]), f2bf(tile[c4 + 3][r]) };
  *(us4v*)(dst + (int64_t)(j0 + r) * 768 + k0 + c4) = o;
}

// ---------------- GEMM: C = A[M,K] * Bt[N,K]^T + bias ----------------
template<int MODE>
__global__ __launch_bounds__(256) void k_gemm(
    const unsigned short* __restrict__ A, const unsigned short* __restrict__ Bt,
    const float* __restrict__ bias, int M, int N, int K,
    unsigned short* __restrict__ qb, unsigned short* __restrict__ kb,
    unsigned short* __restrict__ vtb, float* __restrict__ outp)
{
  __shared__ __align__(16) unsigned short At [128 * 32];
  __shared__ __align__(16) unsigned short Btl[128 * 32];
  const int tid = threadIdx.x, lane = tid & 63, wid = tid >> 6;
  const int mbase = blockIdx.y * 128, nbase = blockIdx.x * 128;
  const int wr = wid >> 1, wc = wid & 1;
  const int g = lane >> 4, l15 = lane & 15;
  const int l2 = lane >> 2, l3 = lane & 3;
  f4v acc[4][4] = {};

  int srow0 = wid * 16 + l2;
  int srow1 = 64 + wid * 16 + l2;
  int sg0 = l3 ^ ((srow0 >> 1) & 3);
  int sg1 = l3 ^ ((srow1 >> 1) & 3);
  int arow0 = mbase + srow0; if (arow0 >= M) arow0 = 0;
  int arow1 = mbase + srow1; if (arow1 >= M) arow1 = 0;
  const unsigned short* a0 = A  + (int64_t)arow0 * K + sg0 * 8;
  const unsigned short* a1 = A  + (int64_t)arow1 * K + sg1 * 8;
  const unsigned short* b0 = Bt + (int64_t)(nbase + srow0) * K + sg0 * 8;
  const unsigned short* b1 = Bt + (int64_t)(nbase + srow1) * K + sg1 * 8;
  unsigned short* lA0 = At  + wid * 16 * 32;
  unsigned short* lA1 = At  + (64 + wid * 16) * 32;
  unsigned short* lB0 = Btl + wid * 16 * 32;
  unsigned short* lB1 = Btl + (64 + wid * 16) * 32;

  for (int ks = 0; ks < K; ks += 32){
    load_lds16(a0 + ks, lA0);
    load_lds16(a1 + ks, lA1);
    load_lds16(b0 + ks, lB0);
    load_lds16(b1 + ks, lB1);
    __syncthreads();
    s8v af[4], bf[4];
    #pragma unroll
    for (int mc = 0; mc < 4; mc++){
      int row = wr * 64 + mc * 16 + l15;
      int o = (row * 64 + g * 16) ^ (((row >> 1) & 3) << 4);
      af[mc] = *(const s8v*)((const char*)At + o);
    }
    #pragma unroll
    for (int nc = 0; nc < 4; nc++){
      int row = wc * 64 + nc * 16 + l15;
      int o = (row * 64 + g * 16) ^ (((row >> 1) & 3) << 4);
      bf[nc] = *(const s8v*)((const char*)Btl + o);
    }
    #pragma unroll
    for (int mc = 0; mc < 4; mc++)
      #pragma unroll
      for (int nc = 0; nc < 4; nc++)
        acc[mc][nc] = mfma32(af[mc], bf[nc], acc[mc][nc]);
    __syncthreads();
  }

  if (MODE == 0){
    const int which = nbase / 768;
    const int head  = ((nbase % 768) >> 6) + wc;
    #pragma unroll
    for (int nc = 0; nc < 4; nc++){
      int j = nbase + wc * 64 + nc * 16 + l15;
      float bv = bias[j];
      int d = nc * 16 + l15;
      #pragma unroll
      for (int mc = 0; mc < 4; mc++){
        int m0 = mbase + wr * 64 + mc * 16 + g * 4;
        if (m0 >= M) continue;
        int b = m0 / 1032, n = m0 % 1032;
        int bh = b * 12 + head;
        if (which == 2){
          us4v pk = { f2bf(acc[mc][nc][0] + bv), f2bf(acc[mc][nc][1] + bv),
                      f2bf(acc[mc][nc][2] + bv), f2bf(acc[mc][nc][3] + bv) };
          *(us4v*)(vtb + ((int64_t)bh * 64 + d) * 1032 + n) = pk;
        } else {
          unsigned short* dst = (which == 0 ? qb : kb) + ((int64_t)bh * 1032 + n) * 64 + d;
          #pragma unroll
          for (int r = 0; r < 4; r++) dst[(int64_t)r * 64] = f2bf(acc[mc][nc][r] + bv);
        }
      }
    }
  } else {
    #pragma unroll
    for (int nc = 0; nc < 4; nc++){
      int j = nbase + wc * 64 + nc * 16 + l15;
      float bv = bias[j];
      #pragma unroll
      for (int mc = 0; mc < 4; mc++){
        int m0 = mbase + wr * 64 + mc * 16 + g * 4;
        if (m0 >= M) continue;
        int b = m0 / 1032, n0 = m0 % 1032;
        #pragma unroll
        for (int r = 0; r < 4; r++){
          int n = n0 + r;
          float v = acc[mc][nc][r] + bv;
          int64_t dst = (n < 8) ? (6291456LL + ((int64_t)(b * 8 + n)) * 768 + j)
                                : (((int64_t)(b * 1024 + (n - 8))) * 768 + j);
          outp[dst] = v;
        }
      }
    }
  }
}

// ---------------- fused rel_h + rel_w (math verbatim r7) ----------------
__global__ __launch_bounds__(64) void k_rel(const unsigned short* __restrict__ qbuf,
    const float* __restrict__ rph, const float* __restrict__ rpw,
    float* __restrict__ relh, float* __restrict__ relw)
{
  const int lane = threadIdx.x;
  const int g = lane >> 4, l15 = lane & 15;
  if (blockIdx.x < 3072){
    const int bh = blockIdx.x >> 5;
    const int qh = blockIdx.x & 31;
    s8v qf[2][2];
    #pragma unroll
    for (int qc = 0; qc < 2; qc++){
      int n = qh * 32 + qc * 16 + l15 + 8;
      #pragma unroll
      for (int ch = 0; ch < 2; ch++)
        qf[qc][ch] = *(const s8v*)(qbuf + ((int64_t)bh * 1032 + n) * 64 + ch * 32 + g * 8);
    }
    s8v rf[2][2];
    #pragma unroll
    for (int kc = 0; kc < 2; kc++){
      int kh = kc * 16 + l15;
      #pragma unroll
      for (int ch = 0; ch < 2; ch++){
        const float* rp = rph + (int64_t)(qh - kh + 31) * 64 + ch * 32 + g * 8;
        f32x4v v0 = *(const f32x4v*)rp;
        f32x4v v1 = *(const f32x4v*)(rp + 4);
        s8v t = { (short)f2bf(v0[0]), (short)f2bf(v0[1]), (short)f2bf(v0[2]), (short)f2bf(v0[3]),
                  (short)f2bf(v1[0]), (short)f2bf(v1[1]), (short)f2bf(v1[2]), (short)f2bf(v1[3]) };
        rf[kc][ch] = t;
      }
    }
    #pragma unroll
    for (int kc = 0; kc < 2; kc++)
      #pragma unroll
      for (int qc = 0; qc < 2; qc++){
        f4v d = {0.f, 0.f, 0.f, 0.f};
        d = mfma32(rf[kc][0], qf[qc][0], d);
        d = mfma32(rf[kc][1], qf[qc][1], d);
        #pragma unroll
        for (int r = 0; r < 4; r++)
          relh[((int64_t)bh * 32 + kc * 16 + g * 4 + r) * 1024 + qh * 32 + qc * 16 + l15] = d[r] * L2E;
      }
  } else {
    const int bid = blockIdx.x - 3072;
    const int bh = bid >> 5;
    const int qw = bid & 31;
    s8v qf[2][2];
    #pragma unroll
    for (int qc = 0; qc < 2; qc++){
      int qp = qw + 32 * (qc * 16 + l15);
      int n = qp + 8;
      #pragma unroll
      for (int ch = 0; ch < 2; ch++)
        qf[qc][ch] = *(const s8v*)(qbuf + ((int64_t)bh * 1032 + n) * 64 + ch * 32 + g * 8);
    }
    s8v wf[2][2];
    #pragma unroll
    for (int kc = 0; kc < 2; kc++){
      int kw = kc * 16 + l15;
      #pragma unroll
      for (int ch = 0; ch < 2; ch++){
        const float* rp = rpw + (int64_t)(qw - kw + 31) * 64 + ch * 32 + g * 8;
        f32x4v v0 = *(const f32x4v*)rp;
        f32x4v v1 = *(const f32x4v*)(rp + 4);
        s8v t = { (short)f2bf(v0[0]), (short)f2bf(v0[1]), (short)f2bf(v0[2]), (short)f2bf(v0[3]),
                  (short)f2bf(v1[0]), (short)f2bf(v1[1]), (short)f2bf(v1[2]), (short)f2bf(v1[3]) };
        wf[kc][ch] = t;
      }
    }
    #pragma unroll
    for (int qc = 0; qc < 2; qc++)
      #pragma unroll
      for (int kc = 0; kc < 2; kc++){
        f4v d = {0.f, 0.f, 0.f, 0.f};
        d = mfma32(qf[qc][0], wf[kc][0], d);
        d = mfma32(qf[qc][1], wf[kc][1], d);
        #pragma unroll
        for (int r = 0; r < 4; r++){
          int qp = qw + 32 * (qc * 16 + g * 4 + r);
          relw[((int64_t)bh * 1024 + qp) * 32 + kc * 16 + l15] = d[r] * L2E;
        }
      }
  }
}

// ---------------- flash attention, LDS-staged K/V shared by 4 waves ----------------
// VERBATIM round-7 version (passed, 70.3 us): single-buffered, inline staging,
// stage -> barrier -> compute -> barrier per k-tile. The r8-r10 restructured
// variants all raced; this exact form is the proven one.
__global__ __launch_bounds__(256, 3) void k_attn(
    const unsigned short* __restrict__ qb, const unsigned short* __restrict__ kb,
    const unsigned short* __restrict__ vtb, const float* __restrict__ relh,
    const float* __restrict__ relw, unsigned short* __restrict__ ao)
{
  const int lane = threadIdx.x & 63, wid = threadIdx.x >> 6;
  // XCD-bijective swizzle: 864 = 8 * 108
  const int wq = (blockIdx.x & 7) * 108 + (blockIdx.x >> 3);
  const int bh = wq / 9;
  const int qg = wq % 9;
  int qt = qg * 4 + wid; if (qt > 32) qt = 32;   // dup waves write identical data
  const int qbase = qt * 32;
  const int g = lane >> 4, l15 = lane & 15;
  const int b = bh / 12, head = bh % 12;
  const float C1 = 0.125f * L2E;
  const float NEG = -144.269504f;   // exp2 -> 0

  __shared__ __align__(16) unsigned short Kl[32 * 64];  // 4KB, row=128B, slot^=(r&7)
  __shared__ __align__(16) unsigned short Vl[64 * 32];  // 4KB, row=64B,  slot^=((d^(d>>2))&3)

  f4v of[4][2] = {};
  float lrun[2] = {0.f, 0.f};
  int qn_[2], qp_[2];

  s8v qf[2][2];
  float rw[2][2][4];
  #pragma unroll
  for (int qc = 0; qc < 2; qc++){
    int qn = qbase + qc * 16 + l15;
    qn_[qc] = qn;
    int qcl = qn < 1032 ? qn : 1031;
    #pragma unroll
    for (int ch = 0; ch < 2; ch++)
      qf[qc][ch] = *(const s8v*)(qb + ((int64_t)bh * 1032 + qcl) * 64 + ch * 32 + g * 8);
    int qp = qn - 8; if (qp < 0) qp = 0; if (qp > 1023) qp = 1023;
    qp_[qc] = qp;
  }
  #pragma unroll
  for (int qc = 0; qc < 2; qc++)
    #pragma unroll
    for (int kc = 0; kc < 2; kc++)
      #pragma unroll
      for (int r = 0; r < 4; r++){
        int kw = (kc * 16 + g * 4 + r + 24) & 31;
        rw[qc][kc][r] = relw[((int64_t)bh * 1024 + qp_[qc]) * 32 + kw];
      }

  const char* kbb = (const char*)(kb + (int64_t)bh * 1032 * 64);
  const char* vbb = (const char*)(vtb + (int64_t)bh * 64 * 1032);
  const float* rhbase = relh + (int64_t)bh * 32 * 1024;

  // staging geometry (per wave; lane's LDS dest = base + lane*16, HW-linear)
  const int krow_l = (lane >> 3);                    // 0..7 within wave's 8 rows
  const int kcol_s = ((lane & 7) ^ krow_l) << 4;     // pre-swizzled col byte
  const int vd_l   = (lane >> 2);                    // 0..15 within wave's 16 rows
  const int vslot  = ((lane & 3) ^ ((lane >> 2) ^ (lane >> 4)) & 3);
  char* kdst = (char*)Kl + wid * 1024;
  char* vdst = (char*)Vl + wid * 1024;
  const int vsw = (l15 ^ (l15 >> 2)) & 3;            // read-side V swizzle

  for (int kt = 0; kt < 33; kt++){
    // ---- stage tile kt (4 waves cooperatively; clamped sources stay finite) ----
    {
      int gr = kt * 32 + wid * 8 + krow_l; if (gr > 1031) gr = 1031;
      load_lds16(kbb + (int64_t)gr * 128 + kcol_s, kdst);
      int d = wid * 16 + vd_l;
      int scol = kt * 64 + (vslot << 4); if (scol > 2048) scol = 2048;
      load_lds16(vbb + (int64_t)d * 2064 + scol, vdst);
    }
    __syncthreads();

    // ---- fragments from LDS ----
    s8v kf[2][2];
    #pragma unroll
    for (int kc = 0; kc < 2; kc++){
      int roff = (kc * 16 + l15) << 7;
      #pragma unroll
      for (int ch = 0; ch < 2; ch++)
        kf[kc][ch] = *(const s8v*)((const char*)Kl + roff + ((((ch << 2) + g) ^ (l15 & 7)) << 4));
    }
    s4v vf[4][2];
    #pragma unroll
    for (int dc = 0; dc < 4; dc++){
      int doff = ((dc * 16 + l15) << 6) + ((g & 1) << 3);
      #pragma unroll
      for (int kc = 0; kc < 2; kc++)
        vf[dc][kc] = *(const s4v*)((const char*)Vl + doff + ((((kc << 1) + (g >> 1)) ^ vsw) << 4));
    }
    // rel_h rows
    int khA = kt - 1; if (khA < 0) khA = 0;
    int khB = kt; if (khB > 31) khB = 31;
    float rhA[2], rhB[2];
    #pragma unroll
    for (int qc = 0; qc < 2; qc++){
      rhA[qc] = rhbase[(int64_t)khA * 1024 + qp_[qc]];
      rhB[qc] = rhbase[(int64_t)khB * 1024 + qp_[qc]];
    }

    // ---- QK^T (swapped: lane col = query) ----
    f4v sv[2][2];
    #pragma unroll
    for (int qc = 0; qc < 2; qc++)
      #pragma unroll
      for (int kc = 0; kc < 2; kc++){
        f4v s = {0.f, 0.f, 0.f, 0.f};
        s = mfma32(kf[kc][0], qf[qc][0], s);
        s = mfma32(kf[kc][1], qf[qc][1], s);
        sv[qc][kc] = s;
      }

    const bool anyprompt = (kt == 0);
    const bool anymask = (kt == 32);
    s4v bp[2][2];
    #pragma unroll
    for (int qc = 0; qc < 2; qc++){
      const bool qpr = qn_[qc] < 8;
      float p[8];
      #pragma unroll
      for (int kc = 0; kc < 2; kc++)
        #pragma unroll
        for (int r = 0; r < 4; r++){
          int off = kc * 16 + g * 4 + r;
          float bias = qpr ? 0.f : ((off >= 8 ? rhB[qc] : rhA[qc]) + rw[qc][kc][r]);
          if (anyprompt && off < 8 && !qpr) bias = NEG;
          float L = fmaf(sv[qc][kc][r], C1, bias);
          if (anymask && off >= 8) L = NEG;
          p[kc * 4 + r] = exp2g(L);
        }
      lrun[qc] += ((p[0]+p[1])+(p[2]+p[3])) + ((p[4]+p[5])+(p[6]+p[7]));
      bp[qc][0] = pack4(p[0], p[1], p[2], p[3]);
      bp[qc][1] = pack4(p[4], p[5], p[6], p[7]);
    }
    // ---- PV ----
    #pragma unroll
    for (int dc = 0; dc < 4; dc++)
      #pragma unroll
      for (int kc = 0; kc < 2; kc++)
        #pragma unroll
        for (int qc = 0; qc < 2; qc++)
          of[dc][qc] = mfma16(vf[dc][kc], bp[qc][kc], of[dc][qc]);

    __syncthreads();   // all waves done reading before next stage overwrites
  }

  // ---- epilogue: l-reduce across g-groups, normalize, store ----
  #pragma unroll
  for (int qc = 0; qc < 2; qc++){
    int qn = qn_[qc];
    if (qn >= 1032) continue;
    float lt = lrun[qc];
    lt += __shfl_xor(lt, 16);
    lt += __shfl_xor(lt, 32);
    float inv = 1.0f / lt;
    unsigned short* dst = ao + ((int64_t)(b * 1032 + qn)) * 768 + head * 64;
    #pragma unroll
    for (int dc = 0; dc < 4; dc++){
      us4v pk = { f2bf(of[dc][qc][0] * inv), f2bf(of[dc][qc][1] * inv),
                  f2bf(of[dc][qc][2] * inv), f2bf(of[dc][qc][3] * inv) };
      *(us4v*)(dst + dc * 16 + g * 4) = pk;
    }
  }
}

extern "C" void kernel_launch(void* const* d_in, const int* in_sizes, int n_in,
                              void* d_out, int out_size, void* d_ws, size_t ws_size,
                              hipStream_t stream)
{
  const float* x   = (const float*)d_in[0];
  const float* vp  = (const float*)d_in[1];
  const float* qw  = (const float*)d_in[2];
  const float* qbb = (const float*)d_in[3];
  const float* pw  = (const float*)d_in[4];
  const float* pb  = (const float*)d_in[5];
  const float* rph = (const float*)d_in[6];
  const float* rpw = (const float*)d_in[7];
  float* out = (float*)d_out;

  char* ws = (char*)d_ws;
  size_t off = 0;
  auto alloc = [&](size_t bytes) -> void* {
    void* p = ws + off;
    off = (off + bytes + 255) & ~(size_t)255;
    return p;
  };
  unsigned short* xs   = (unsigned short*)alloc((size_t)8256 * 768 * 2);
  unsigned short* Wt   = (unsigned short*)alloc((size_t)2304 * 768 * 2);
  unsigned short* Pt   = (unsigned short*)alloc((size_t)768 * 768 * 2);
  unsigned short* qbuf = (unsigned short*)alloc((size_t)96 * 1032 * 64 * 2);
  unsigned short* kbuf = (unsigned short*)alloc((size_t)96 * 1032 * 64 * 2 + 4096);
  unsigned short* vtb  = (unsigned short*)alloc((size_t)96 * 64 * 1032 * 2 + 4096);
  float* relh = (float*)alloc((size_t)96 * 32 * 1024 * 4);
  float* relw = (float*)alloc((size_t)96 * 1024 * 32 * 4);
  unsigned short* ao = xs;  // xs dead after QKV GEMM; reuse for attention output

  k_prep<<<8496, 256, 0, stream>>>(x, vp, qw, pw, xs, Wt, Pt);
  k_gemm<0><<<dim3(18, 65), 256, 0, stream>>>(xs, Wt, qbb, 8256, 2304, 768,
                                              qbuf, kbuf, vtb, nullptr);
  k_rel<<<6144, 64, 0, stream>>>(qbuf, rph, rpw, relh, relw);
  k_attn<<<864, 256, 0, stream>>>(qbuf, kbuf, vtb, relh, relw, ao);
  k_gemm<1><<<dim3(6, 65), 256, 0, stream>>>(ao, Pt, pb, 8256, 768, 768,
                                             nullptr, nullptr, nullptr, out);
}